// Round 19
// baseline (1347.408 us; speedup 1.0000x reference)
//
#include <hip/hip_runtime.h>
#include <hip/hip_bf16.h>
#include <math.h>
#include <stdint.h>

// ---------------- types ----------------
typedef __bf16 bf16;
typedef __bf16 bf16x8 __attribute__((ext_vector_type(8)));
typedef float  f32x4  __attribute__((ext_vector_type(4)));

// ---------------- model constants ----------------
#define NB   32        // batch
#define ED   768       // embed dim
#define NH   12        // heads
#define DHD  64        // head dim
#define FFD  3072
#define TT1  196       // pre-stack tokens
#define TT2  41        // short-stack tokens
#define TPM  208       // padded token dim (rk row stride)
#define MM1  6272      // 196*32  (= 49*128)
#define MM2  1408      // padded 41*32=1312 -> 11*128
#define M2R  1312
#define BHN  384       // 32*12
#define LTOT 10
#define SCL  0.125f    // 1/sqrt(64)
#define VTS  224       // vT global col stride (padded tokens)
#define SLP  201       // attn_pre S row stride (odd -> bank-spread), 32*201*4 = 25.1 KB

// ---------------- async global->LDS (16B per lane, wave-uniform LDS base) ----------------
__device__ __forceinline__ void gload_lds16(const bf16* g, bf16* l) {
  __builtin_amdgcn_global_load_lds(
      (__attribute__((address_space(1))) void*)(uintptr_t)g,
      (__attribute__((address_space(3))) void*)(uint32_t)(uintptr_t)l,
      16, 0, 0);
}

// ---------------- helpers ----------------
__device__ __forceinline__ float block_sum(float v, float* red, int tid) {
#pragma unroll
  for (int o = 32; o; o >>= 1) v += __shfl_xor(v, o);
  if ((tid & 63) == 0) red[tid >> 6] = v;
  __syncthreads();
  float t = red[0] + red[1] + red[2] + red[3];
  __syncthreads();
  return t;
}

// tanh-form GELU: |err| vs exact erf-GELU ~3e-4, far under the 2.17e-2 threshold.
__device__ __forceinline__ float gelu_f(float v) {
  const float u = v * (0.7978845608f + 0.0356774081f * v * v);
  const float t = 1.0f - 2.0f / (__expf(2.0f * u) + 1.0f);
  return 0.5f * v * (1.0f + t);
}

__device__ __forceinline__ bf16x8 cvt8(const float* __restrict__ s) {
  const f32x4 a = *(const f32x4*)s;
  const f32x4 b = *(const f32x4*)(s + 4);
  bf16x8 o;
#pragma unroll
  for (int j = 0; j < 4; ++j) { o[j] = (bf16)a[j]; o[4 + j] = (bf16)b[j]; }
  return o;
}

// ---------------- fp32 -> bf16 converters (vectorized, n % 8 == 0) ----------------
__global__ void k_cvt(const float* __restrict__ s, bf16* __restrict__ d, long n8) {
  for (long i = (long)blockIdx.x * 256 + threadIdx.x; i < n8; i += (long)gridDim.x * 256)
    *(bf16x8*)&d[i * 8] = cvt8(&s[i * 8]);
}

__global__ void k_cvt4(const float* __restrict__ a, const float* __restrict__ b,
                       const float* __restrict__ c, const float* __restrict__ d,
                       bf16* __restrict__ oa, bf16* __restrict__ ob,
                       bf16* __restrict__ oc, bf16* __restrict__ od,
                       int na8, int nb8, int nc8, int nd8) {
  const long tot = (long)na8 + nb8 + nc8 + nd8;
  for (long i = (long)blockIdx.x * 256 + threadIdx.x; i < tot; i += (long)gridDim.x * 256) {
    if (i < na8) *(bf16x8*)&oa[i * 8] = cvt8(&a[i * 8]);
    else if (i < (long)na8 + nb8) { const long j = i - na8; *(bf16x8*)&ob[j * 8] = cvt8(&b[j * 8]); }
    else if (i < (long)na8 + nb8 + nc8) { const long j = i - na8 - nb8; *(bf16x8*)&oc[j * 8] = cvt8(&c[j * 8]); }
    else { const long j = i - na8 - nb8 - nc8; *(bf16x8*)&od[j * 8] = cvt8(&d[j * 8]); }
  }
}

// ---------------- sinusoidal pos emb (descending pos), bf16 out ----------------
__global__ void k_posemb(bf16* __restrict__ out, int T) {
  const int t = blockIdx.x, c = threadIdx.x;   // block = 768
  float v = 0.0f;
  if (t < T) {
    const float pos = (float)(T - 1 - t);
    const int ci = (c < 384) ? c : c - 384;
    const float invf = expf(-(float)ci * (9.210340371976184f / 384.0f)); // ln(10000)
    const float a = pos * invf;
    v = (c < 384) ? sinf(a) : cosf(a);
  }
  out[(long)t * ED + c] = (bf16)v;
}

// ---------------- im2col for patch embed: A0[t*32+b][c*256+i*16+j] ----------------
__global__ void k_im2col(const float* __restrict__ x, bf16* __restrict__ A0) {
  const long idx = (long)blockIdx.x * 256 + threadIdx.x;
  if (idx >= (long)MM1 * ED) return;
  const int row = (int)(idx / ED), k = (int)(idx % ED);
  const int t = row >> 5, b = row & 31;
  const int c = k >> 8, rem = k & 255, i = rem >> 4, j = rem & 15;
  const int py = t / 14, px = t % 14;
  A0[idx] = (bf16)x[((long)(b * 3 + c) * 224 + (py * 16 + i)) * 224 + px * 16 + j];
}

// ---------------- GEMM: C[m,n] = sum_k A[m,k]*B[n,k] + bias[n] ----------------
// 128x128 tile, BK=32, 4 waves, 3-buffer counted-vmcnt pipeline (T3+T4).
// Bijective XCD-chunked remap of the ROW-MAJOR flat tile index (m204).
// EPI: 0=fp32; 1=GELU->bf16; 2=fp32+bf16; 3=bf16; 4=fp32 partial (split-K).
template <int EPI>
__global__ __launch_bounds__(256) void k_gemm(const bf16* __restrict__ A, const bf16* __restrict__ Bw,
                                              const float* __restrict__ bias,
                                              float* __restrict__ Cf, bf16* __restrict__ Cb,
                                              int M, int N, int K, int LDK) {
  __shared__ __align__(16) bf16 As[3][128 * 32];
  __shared__ __align__(16) bf16 Bs[3][128 * 32];
  const int tid = threadIdx.x;
  const int l = tid & 63, w = tid >> 6;
  const int wr = w >> 1, wc = w & 1;

  // XCD-chunked bijective remap (row-major flat; consecutive logicals share A panel)
  const int gx = gridDim.x;
  const int nwg = gx * gridDim.y;
  const int dph = blockIdx.y * gx + blockIdx.x;   // physical dispatch id (x fastest)
  const int xcd = dph & 7, idx = dph >> 3;
  const int qq = nwg >> 3, rr = nwg & 7;
  const int logical = (xcd < rr ? xcd * (qq + 1) : rr * (qq + 1) + (xcd - rr) * qq) + idx;
  const int by = logical / gx;
  const int m0 = by * 128, n0 = (logical - by * gx) * 128;

  const long koff = (long)blockIdx.z * K;
  const int srow = l >> 2;
  const int scol = ((l & 3) ^ ((l >> 3) & 3)) * 8;
  f32x4 acc[4][4] = {};
  const int nt = K >> 5;

  auto stage = [&](int t, int b) {
    const int kt = t << 5;
#pragma unroll
    for (int p = 0; p < 2; ++p) {
      const int rbase = w * 32 + p * 16;
      gload_lds16(&A[(long)(m0 + rbase + srow) * LDK + koff + kt + scol], &As[b][rbase * 32]);
      gload_lds16(&Bw[(long)(n0 + rbase + srow) * LDK + koff + kt + scol], &Bs[b][rbase * 32]);
    }
  };

  stage(0, 0);
  stage(1, 1);

  int cur = 0;
  for (int t = 0; t < nt; ++t) {
    if (t + 2 < nt) {
      stage(t + 2, cur == 0 ? 2 : cur - 1);
      asm volatile("s_waitcnt vmcnt(8)" ::: "memory");
    } else if (t + 1 < nt) {
      asm volatile("s_waitcnt vmcnt(4)" ::: "memory");
    } else {
      asm volatile("s_waitcnt vmcnt(0)" ::: "memory");
    }
    __builtin_amdgcn_s_barrier();
    {
      bf16x8 af[4], bg[4];
      const int ub = l >> 4;
#pragma unroll
      for (int m = 0; m < 4; ++m) {
        const int row = wr * 64 + m * 16 + (l & 15);
        af[m] = *(const bf16x8*)&As[cur][row * 32 + (ub ^ ((row >> 1) & 3)) * 8];
      }
#pragma unroll
      for (int n = 0; n < 4; ++n) {
        const int row = wc * 64 + n * 16 + (l & 15);
        bg[n] = *(const bf16x8*)&Bs[cur][row * 32 + (ub ^ ((row >> 1) & 3)) * 8];
      }
#pragma unroll
      for (int m = 0; m < 4; ++m)
#pragma unroll
        for (int n = 0; n < 4; ++n)
          acc[m][n] = __builtin_amdgcn_mfma_f32_16x16x32_bf16(af[m], bg[n], acc[m][n], 0, 0, 0);
    }
    asm volatile("s_waitcnt lgkmcnt(0)" ::: "memory");
    __builtin_amdgcn_s_barrier();
    cur = (cur == 2) ? 0 : cur + 1;
  }

  const long pbase = (EPI == 4) ? (long)blockIdx.z * M * N : 0;
#pragma unroll
  for (int m = 0; m < 4; ++m) {
    const int row = m0 + wr * 64 + m * 16 + 4 * (l >> 4);
#pragma unroll
    for (int n = 0; n < 4; ++n) {
      const int col = n0 + wc * 64 + n * 16 + (l & 15);
      const float bv = (EPI == 4) ? 0.0f : bias[col];
#pragma unroll
      for (int r = 0; r < 4; ++r) {
        const float v = acc[m][n][r] + bv;
        const long off = (long)(row + r) * N + col;
        if (EPI == 0) {
          Cf[off] = v;
        } else if (EPI == 1) {
          Cb[off] = (bf16)gelu_f(v);
        } else if (EPI == 2) {
          Cf[off] = v;
          Cb[off] = (bf16)v;
        } else if (EPI == 3) {
          Cb[off] = (bf16)v;
        } else {
          Cf[pbase + off] = v;
        }
      }
    }
  }
}

// ---------------- split-K reduce + bias + residual + LayerNorm ----------------
__global__ __launch_bounds__(256) void k_redk_ln(const float* __restrict__ P, const float* __restrict__ bias,
                                                 const float* __restrict__ g, const float* __restrict__ bb,
                                                 const float* __restrict__ xin,
                                                 float* __restrict__ xo, bf16* __restrict__ xbo,
                                                 int KS, long MN, int Mreal) {
  const int row = blockIdx.x, tid = threadIdx.x;
  const long base = (long)row * ED;
  __shared__ float red[4];
  if (row >= Mreal) {
#pragma unroll
    for (int e = 0; e < 3; ++e) { xo[base + tid + e * 256] = 0.0f; xbo[base + tid + e * 256] = (bf16)0.0f; }
    return;
  }
  float v[3];
#pragma unroll
  for (int e = 0; e < 3; ++e) {
    const int c = tid + e * 256;
    float a = bias[c] + xin[base + c];
    for (int ks = 0; ks < KS; ++ks) a += P[(long)ks * MN + base + c];
    v[e] = a;
  }
  const float mean = block_sum(v[0] + v[1] + v[2], red, tid) * (1.0f / ED);
  float sq = 0.0f;
#pragma unroll
  for (int e = 0; e < 3; ++e) { const float dd = v[e] - mean; sq += dd * dd; }
  const float var = block_sum(sq, red, tid) * (1.0f / ED);
  const float rs = rsqrtf(var + 1e-5f);
#pragma unroll
  for (int e = 0; e < 3; ++e) {
    const int c = tid + e * 256;
    const float o = (v[e] - mean) * rs * g[c] + bb[c];
    xo[base + c] = o;
    xbo[base + c] = (bf16)o;
  }
}

// ---------------- V repack (pre layers): heads V -> global vT[bh][64][VTS] ----------------
__global__ __launch_bounds__(256) void k_vrepack(const bf16* __restrict__ heads, bf16* __restrict__ vT) {
  const int bh = blockIdx.x;
  const int b = bh / NH, n = bh % NH;
  const int tid = threadIdx.x;
  __shared__ __align__(16) bf16 vTl[64 * 232];
  for (int task = tid; task < 224 * 8; task += 256) {
    const int j = task >> 3, c8 = (task & 7) * 8;
    bf16x8 vv = {};
    if (j < TT1) vv = *(const bf16x8*)&heads[((long)(j * NB + b)) * (3 * ED) + 2 * ED + n * 64 + c8];
#pragma unroll
    for (int e = 0; e < 8; ++e) {
      const int d = c8 + e;
      vTl[d * 232 + (j ^ (((d >> 3) & 3) << 3))] = vv[e];
    }
  }
  __syncthreads();
  bf16* dst = vT + (long)bh * 64 * VTS;
  for (int task = tid; task < 64 * 28; task += 256) {
    const int d = task / 28, u = task % 28;
    const int j0 = u * 8;
    const int x = ((d >> 3) & 3) << 3;
    *(bf16x8*)&dst[d * VTS + j0] = *(const bf16x8*)&vTl[d * 232 + (j0 ^ x)];
  }
}

// ---------------- fused PRE-stack attention: 1-D grid 2688 = 8 XCD groups x 336 ----------------
// r19: Sl stride 209 -> 201 (odd, bank-spread preserved); LDS ~26.9 KB -> 6 blocks/CU.
// probl overlays Sl storage (barrier-separated aliasing, r18).
// Div-free rel-shift scatter (s = a+b+1): s<T -> S[a-1][s] (a>=1); s>=T -> S[a][s-T].
__global__ __launch_bounds__(256) void k_attn_pre(
    const bf16* __restrict__ heads, const float* __restrict__ rwb, const float* __restrict__ rrb,
    const bf16* __restrict__ rkb_l, const bf16* __restrict__ vT, bf16* __restrict__ avb) {
  const int dsp = blockIdx.x;
  const int logical = (dsp & 7) * 336 + (dsp >> 3);
  const int bh = logical / 7;
  const int r0 = (logical - bh * 7) * 32;
  const int b = bh / NH, n = bh % NH;
  const int tid = threadIdx.x;
  const int l = tid & 63, w = tid >> 6;
  const int fr = l & 15;
  const int fc = 8 * (l >> 4);
  __shared__ __align__(16) char smem[32 * SLP * 4];   // Sl (fp32) overlaid with probl (bf16)
  float* Sl = (float*)smem;
  bf16* probl = (bf16*)smem;                          // [32][232] bf16 = 14.8 KB < 25.1 KB
  __shared__ float red8[256];
  __shared__ float rstat[32];

  // ---- phase 1: AC ----
  {
    const int ti = w & 1;
    const int ar = r0 + ti * 16 + fr;
    bf16x8 qa0 = {}, qa1 = {};
    if (ar < TT1) {
      const bf16* qp = &heads[((long)(ar * NB + b)) * (3 * ED) + n * 64];
      qa0 = *(const bf16x8*)(qp + fc);
      qa1 = *(const bf16x8*)(qp + 32 + fc);
    }
    bf16x8 q0, q1;
#pragma unroll
    for (int e = 0; e < 8; ++e) {
      q0[e] = (bf16)((float)qa0[e] + rwb[n * 64 + fc + e]);
      q1[e] = (bf16)((float)qa1[e] + rwb[n * 64 + 32 + fc + e]);
    }
    auto ldk = [&](int tj, bf16x8& k0, bf16x8& k1) {
      const int br = tj * 16 + fr;
      k0 = bf16x8{}; k1 = bf16x8{};
      if (br < TT1) {
        const bf16* kp = &heads[((long)(br * NB + b)) * (3 * ED) + ED + n * 64];
        k0 = *(const bf16x8*)(kp + fc);
        k1 = *(const bf16x8*)(kp + 32 + fc);
      }
    };
    bf16x8 k0, k1, nk0, nk1;
    const int tj0 = w >> 1;
    ldk(tj0, k0, k1);
    for (int tj = tj0; tj < 13; tj += 2) {
      if (tj + 2 < 13) ldk(tj + 2, nk0, nk1);
      f32x4 c = {};
      c = __builtin_amdgcn_mfma_f32_16x16x32_bf16(q0, k0, c, 0, 0, 0);
      c = __builtin_amdgcn_mfma_f32_16x16x32_bf16(q1, k1, c, 0, 0, 0);
      const int scol = tj * 16 + fr;
      const int srb = ti * 16 + 4 * (l >> 4);
#pragma unroll
      for (int r = 0; r < 4; ++r) Sl[(srb + r) * SLP + scol] = SCL * c[r];
      k0 = nk0; k1 = nk1;
    }
  }
  __syncthreads();

  // ---- phase 2: BD with div-free scatter ----
  {
    bf16x8 qr0[3], qr1[3];
#pragma unroll
    for (int ta = 0; ta < 3; ++ta) {
      const int ar = r0 + ta * 16 + fr;
      bf16x8 qa0 = {}, qa1 = {};
      if (ar < TT1) {
        const bf16* qp = &heads[((long)(ar * NB + b)) * (3 * ED) + n * 64];
        qa0 = *(const bf16x8*)(qp + fc);
        qa1 = *(const bf16x8*)(qp + 32 + fc);
      }
#pragma unroll
      for (int e = 0; e < 8; ++e) {
        qr0[ta][e] = (bf16)((float)qa0[e] + rrb[n * 64 + fc + e]);
        qr1[ta][e] = (bf16)((float)qa1[e] + rrb[n * 64 + 32 + fc + e]);
      }
    }
    auto ldr = [&](int tb, bf16x8& g0, bf16x8& g1) {
      const int br = tb * 16 + fr;
      const bf16* rp = &rkb_l[((long)n * TPM + br) * 64];
      g0 = *(const bf16x8*)(rp + fc);
      g1 = *(const bf16x8*)(rp + 32 + fc);
    };
    bf16x8 g0, g1, ng0, ng1;
    if (w < 13) ldr(w, g0, g1);
    for (int tb = w; tb < 13; tb += 4) {
      if (tb + 4 < 13) ldr(tb + 4, ng0, ng1);
#pragma unroll
      for (int ta = 0; ta < 3; ++ta) {
        f32x4 c = {};
        c = __builtin_amdgcn_mfma_f32_16x16x32_bf16(qr0[ta], g0, c, 0, 0, 0);
        c = __builtin_amdgcn_mfma_f32_16x16x32_bf16(qr1[ta], g1, c, 0, 0, 0);
        const int bcol = tb * 16 + fr;
        const int ab = r0 + ta * 16 + 4 * (l >> 4);
#pragma unroll
        for (int r = 0; r < 4; ++r) {
          const int a = ab + r;
          if (a < TT1 && bcol < TT1) {
            const int s = a + bcol + 1;
            const int i = (s < TT1) ? (a - 1) : a;
            const int j = (s < TT1) ? s : (s - TT1);
            const int li = i - r0;
            if (li >= 0 && li < 32) Sl[li * SLP + j] += SCL * c[r];
          }
        }
      }
      g0 = ng0; g1 = ng1;
    }
  }
  __syncthreads();

  // ---- phase 3: row softmax (8 threads per row); P staged in regs, then alias write ----
  const int sr = tid & 31, sg = tid >> 5;
  const bool rowok = (r0 + sr) < TT1;
  const int j0 = sg * 25;
  const int j1 = (j0 + 25 < TT1) ? j0 + 25 : TT1;
  float pm = -3.0e38f;
  if (rowok) {
    for (int j = j0; j < j1; ++j) pm = fmaxf(pm, Sl[sr * SLP + j]);
  }
  red8[sr * 8 + sg] = pm;
  __syncthreads();
  if (tid < 32) {
    float m0 = red8[tid * 8];
#pragma unroll
    for (int q = 1; q < 8; ++q) m0 = fmaxf(m0, red8[tid * 8 + q]);
    rstat[tid] = m0;
  }
  __syncthreads();
  const float rm = rstat[sr];
  float ps = 0.0f;
  if (rowok) {
    for (int j = j0; j < j1; ++j) {
      const float e = __expf(Sl[sr * SLP + j] - rm);
      Sl[sr * SLP + j] = e;
      ps += e;
    }
  }
  red8[sr * 8 + sg] = ps;
  __syncthreads();
  if (tid < 32) {
    float s0 = 0.0f;
#pragma unroll
    for (int q = 0; q < 8; ++q) s0 += red8[tid * 8 + q];
    rstat[tid] = (s0 > 0.0f) ? 1.0f / s0 : 0.0f;
  }
  __syncthreads();
  {
    const float inv = rstat[sr];
    const int sx = ((sr >> 3) & 3) << 3;
    bf16 hreg[28];
#pragma unroll
    for (int u = 0; u < 28; ++u) {
      const int j = sg * 28 + u;
      const float v = (rowok && j < TT1) ? Sl[sr * SLP + j] * inv : 0.0f;
      hreg[u] = (bf16)v;
    }
    __syncthreads();   // all Sl reads complete before alias writes
#pragma unroll
    for (int u = 0; u < 28; ++u) {
      const int j = sg * 28 + u;
      probl[sr * 232 + (j ^ sx)] = hreg[u];
    }
  }
  __syncthreads();

  // ---- phase 4: PV (P from aliased LDS, V from global vT) ----
  const bf16* vTg = vT + (long)bh * 64 * VTS;
  for (int tt = w; tt < 8; tt += 4) {
    const int ti = tt & 1, dj = tt >> 1;
    const int prow = ti * 16 + fr;
    const int vrow = dj * 16 + fr;
    const int px = ((prow >> 3) & 3) << 3;
    f32x4 c = {};
#pragma unroll
    for (int kk = 0; kk < 224; kk += 32) {
      const int j0v = kk + fc;
      const bf16x8 pa = *(const bf16x8*)&probl[prow * 232 + (j0v ^ px)];
      const bf16x8 vb = *(const bf16x8*)&vTg[vrow * VTS + j0v];
      c = __builtin_amdgcn_mfma_f32_16x16x32_bf16(pa, vb, c, 0, 0, 0);
    }
    const int d = dj * 16 + fr;
    const int ib = ti * 16 + 4 * (l >> 4);
#pragma unroll
    for (int r = 0; r < 4; ++r) {
      const int gi = r0 + ib + r;
      if (gi < TT1) avb[((long)(gi * NB + b)) * ED + n * 64 + d] = (bf16)c[r];
    }
  }
}

// ---------------- fused short-stack attention: one block per (b,h), T=41 ----------------
__global__ __launch_bounds__(256) void k_attn_short(
    const bf16* __restrict__ heads, const float* __restrict__ rwb, const float* __restrict__ rrb,
    const bf16* __restrict__ rkb_l, bf16* __restrict__ avb) {
  const int bh = blockIdx.x;
  const int b = bh / NH, n = bh % NH;
  const int tid = threadIdx.x;
  const int l = tid & 63, w = tid >> 6;
  const int fr = l & 15, fc = 8 * (l >> 4);
  __shared__ float Sl[48 * 49];
  __shared__ __align__(16) bf16 probl[48 * 72];
  __shared__ __align__(16) bf16 vTl[64 * 72];

  for (int task = tid; task < 64 * 8; task += 256) {
    const int j = task >> 3, c8 = (task & 7) * 8;
    bf16x8 vv = {};
    if (j < TT2) vv = *(const bf16x8*)&heads[((long)(j * NB + b)) * (3 * ED) + 2 * ED + n * 64 + c8];
#pragma unroll
    for (int e = 0; e < 8; ++e) {
      const int d = c8 + e;
      vTl[d * 72 + (j ^ (((d >> 3) & 3) << 3))] = vv[e];
    }
  }

  for (int tt = w; tt < 9; tt += 4) {
    const int ti = tt / 3, tj = tt % 3;
    const int ar = ti * 16 + fr;
    const int br = tj * 16 + fr;
    f32x4 c = {};
#pragma unroll
    for (int kk = 0; kk < 64; kk += 32) {
      const int col = kk + fc;
      bf16x8 qa = {}, kb = {};
      if (ar < 44) qa = *(const bf16x8*)&heads[((long)(ar * NB + b)) * (3 * ED) + n * 64 + col];
      if (br < 44) kb = *(const bf16x8*)&heads[((long)(br * NB + b)) * (3 * ED) + ED + n * 64 + col];
      bf16x8 qq;
#pragma unroll
      for (int e = 0; e < 8; ++e) qq[e] = (bf16)((float)qa[e] + rwb[n * 64 + col + e]);
      c = __builtin_amdgcn_mfma_f32_16x16x32_bf16(qq, kb, c, 0, 0, 0);
    }
    const int scol = tj * 16 + fr;
    const int srb = ti * 16 + 4 * (l >> 4);
#pragma unroll
    for (int r = 0; r < 4; ++r) Sl[(srb + r) * 49 + scol] = SCL * c[r];
  }
  __syncthreads();

  for (int tt = w; tt < 9; tt += 4) {
    const int ti = tt / 3, tj = tt % 3;
    const int ar = ti * 16 + fr;
    const int br = tj * 16 + fr;
    f32x4 c = {};
#pragma unroll
    for (int kk = 0; kk < 64; kk += 32) {
      const int col = kk + fc;
      bf16x8 qa = {};
      if (ar < 44) qa = *(const bf16x8*)&heads[((long)(ar * NB + b)) * (3 * ED) + n * 64 + col];
      const bf16x8 rk = *(const bf16x8*)&rkb_l[((long)n * TPM + br) * 64 + col];
      bf16x8 qq;
#pragma unroll
      for (int e = 0; e < 8; ++e) qq[e] = (bf16)((float)qa[e] + rrb[n * 64 + col + e]);
      c = __builtin_amdgcn_mfma_f32_16x16x32_bf16(qq, rk, c, 0, 0, 0);
    }
    const int bcol = tj * 16 + fr;
    const int ab = ti * 16 + 4 * (l >> 4);
#pragma unroll
    for (int r = 0; r < 4; ++r) {
      const int a = ab + r;
      if (a < TT2 && bcol < TT2) {
        const int s = a + bcol + 1;
        const int i = (s < TT2) ? (a - 1) : a;
        const int j = (s < TT2) ? s : (s - TT2);
        if (i >= 0) Sl[i * 49 + j] += SCL * c[r];
      }
    }
  }
  __syncthreads();

  if (tid < 48) {
    const int i = tid;
    const int ix = ((i >> 3) & 3) << 3;
    if (i < TT2) {
      float mx = -3.0e38f;
      for (int j = 0; j < TT2; ++j) mx = fmaxf(mx, Sl[i * 49 + j]);
      float sm = 0.0f;
      for (int j = 0; j < TT2; ++j) { const float e = expf(Sl[i * 49 + j] - mx); Sl[i * 49 + j] = e; sm += e; }
      const float inv = 1.0f / sm;
      for (int j = 0; j < TT2; ++j) probl[i * 72 + (j ^ ix)] = (bf16)(Sl[i * 49 + j] * inv);
      for (int j = TT2; j < 64; ++j) probl[i * 72 + (j ^ ix)] = (bf16)0.0f;
    } else {
      for (int j = 0; j < 64; ++j) probl[i * 72 + (j ^ ix)] = (bf16)0.0f;
    }
  }
  __syncthreads();

  for (int tt = w; tt < 12; tt += 4) {
    const int ti = tt % 3, dj = tt / 3;
    const int prow = ti * 16 + fr;
    const int vrow = dj * 16 + fr;
    const int px = ((prow >> 3) & 3) << 3;
    const int vx = ((vrow >> 3) & 3) << 3;
    f32x4 c = {};
#pragma unroll
    for (int kk = 0; kk < 64; kk += 32) {
      const int j0 = kk + fc;
      const bf16x8 pa = *(const bf16x8*)&probl[prow * 72 + (j0 ^ px)];
      const bf16x8 vb = *(const bf16x8*)&vTl[vrow * 72 + (j0 ^ vx)];
      c = __builtin_amdgcn_mfma_f32_16x16x32_bf16(pa, vb, c, 0, 0, 0);
    }
    const int d = dj * 16 + fr;
    const int ib = ti * 16 + 4 * (l >> 4);
#pragma unroll
    for (int r = 0; r < 4; ++r) {
      const int i = ib + r;
      if (i < TT2) avb[((long)(i * NB + b)) * ED + n * 64 + d] = (bf16)c[r];
    }
  }
}

// ---------------- rk repack: rkall fp32 [rows][nl*768] -> rkb bf16 [l][n][TPM][64] ----------------
__global__ void k_rkrepack(const float* __restrict__ rkall, bf16* __restrict__ rkb,
                           int T, int Ncols, int l0) {
  const int i = blockIdx.x, z = blockIdx.y, d = threadIdx.x;  // block = 768
  const float v = (i < T) ? rkall[(long)i * Ncols + z * ED + d] : 0.0f;
  const int n = d >> 6, dh = d & 63;
  rkb[(((long)(l0 + z) * NH + n) * TPM + i) * 64 + dh] = (bf16)v;
}

// ---------------- downsample: segment-mean pool + null token + LN ----------------
__global__ __launch_bounds__(256) void k_down(const float* __restrict__ x, const float* __restrict__ nullt,
                                              const float* __restrict__ g, const float* __restrict__ bb,
                                              float* __restrict__ xo, bf16* __restrict__ xbo) {
  const int row = blockIdx.x, tid = threadIdx.x;
  const long base = (long)row * ED;
  __shared__ float red[4];
  if (row >= TT2 * NB) {
#pragma unroll
    for (int e = 0; e < 3; ++e) { xo[base + tid + e * 256] = 0.0f; xbo[base + tid + e * 256] = (bf16)0.0f; }
    return;
  }
  const int s = row >> 5, b = row & 31;
  float v[3];
  if (s == 0) {
#pragma unroll
    for (int e = 0; e < 3; ++e) v[e] = nullt[tid + e * 256];
  } else {
    const int seg = s - 1;
    const int t0 = (seg == 0) ? 0 : (5 * seg - 4);
    const int cnt = (seg == 0) ? 1 : 5;
#pragma unroll
    for (int e = 0; e < 3; ++e) {
      float a = 0.0f;
      for (int tt = 0; tt < cnt; ++tt) a += x[((long)((t0 + tt) * NB + b)) * ED + tid + e * 256];
      v[e] = a / (float)cnt;
    }
  }
  const float mean = block_sum(v[0] + v[1] + v[2], red, tid) * (1.0f / ED);
  float sq = 0.0f;
#pragma unroll
  for (int e = 0; e < 3; ++e) { const float dd = v[e] - mean; sq += dd * dd; }
  const float var = block_sum(sq, red, tid) * (1.0f / ED);
  const float rs = rsqrtf(var + 1e-5f);
#pragma unroll
  for (int e = 0; e < 3; ++e) {
    const int c = tid + e * 256;
    const float o = (v[e] - mean) * rs * g[c] + bb[c];
    xo[base + c] = o;
    xbo[base + c] = (bf16)o;
  }
}

// ---------------- final token mean (fp32) ----------------
__global__ __launch_bounds__(256) void k_mean(const float* __restrict__ x2, float* __restrict__ xm) {
  const int b = blockIdx.x, tid = threadIdx.x;
#pragma unroll
  for (int e = 0; e < 3; ++e) {
    const int c = tid + e * 256;
    float a = 0.0f;
    for (int s = 0; s < TT2; ++s) a += x2[((long)(s * NB + b)) * ED + c];
    xm[(long)b * ED + c] = a * (1.0f / TT2);
  }
}

// ---------------- classifier head (fp32 dot, wave per (b,n)) ----------------
__global__ __launch_bounds__(256) void k_head(const float* __restrict__ xm, const float* __restrict__ hw,
                                              const float* __restrict__ hbias, float* __restrict__ out) {
  const int gid = blockIdx.x * 4 + (threadIdx.x >> 6);
  const int l = threadIdx.x & 63;
  if (gid >= NB * 1000) return;
  const int b = gid / 1000, n = gid % 1000;
  const float* xr = xm + (long)b * ED;
  const float* wr = hw + (long)n * ED;
  float a = 0.0f;
#pragma unroll
  for (int e = 0; e < 12; ++e) a += xr[l + 64 * e] * wr[l + 64 * e];
#pragma unroll
  for (int o = 32; o; o >>= 1) a += __shfl_xor(a, o);
  if (l == 0) out[(long)b * 1000 + n] = a + hbias[n];
}

// =======================================================================
extern "C" void kernel_launch(void* const* d_in, const int* in_sizes, int n_in,
                              void* d_out, int out_size, void* d_ws, size_t ws_size,
                              hipStream_t stream) {
  const float* in_x     = (const float*)d_in[0];
  const float* patch_w  = (const float*)d_in[1];
  const float* patch_b  = (const float*)d_in[2];
  const float* r_w_bias = (const float*)d_in[3];
  const float* r_r_bias = (const float*)d_in[4];
  const float* qkv_w    = (const float*)d_in[5];
  const float* qkv_b    = (const float*)d_in[6];
  const float* rnet_w   = (const float*)d_in[7];
  const float* rnet_b   = (const float*)d_in[8];
  const float* onet_w   = (const float*)d_in[9];
  const float* onet_b   = (const float*)d_in[10];
  const float* ln1_g    = (const float*)d_in[11];
  const float* ln1_b    = (const float*)d_in[12];
  const float* ff1_w    = (const float*)d_in[13];
  const float* ff1_b    = (const float*)d_in[14];
  const float* ff2_w    = (const float*)d_in[15];
  const float* ff2_b    = (const float*)d_in[16];
  const float* ln2_g    = (const float*)d_in[17];
  const float* ln2_b    = (const float*)d_in[18];
  const float* null_tok = (const float*)d_in[19];
  const float* down_g   = (const float*)d_in[20];
  const float* down_b   = (const float*)d_in[21];
  const float* head_w   = (const float*)d_in[22];
  const float* head_b   = (const float*)d_in[23];
  float* out = (float*)d_out;

  char* base = (char*)d_ws;
  size_t off = 0;
  auto take = [&](size_t bytes) -> char* {
    char* r = base + off;
    off += (bytes + 255) & ~(size_t)255;
    return r;
  };

  // persistent
  float* x    = (float*)take((size_t)MM1 * ED * 4);
  bf16*  xb   = (bf16*)take((size_t)MM1 * ED * 2);
  float* x2   = (float*)take((size_t)MM2 * ED * 4);
  bf16*  xb2  = (bf16*)take((size_t)MM2 * ED * 2);
  bf16*  rkb  = (bf16*)take((size_t)LTOT * NH * TPM * 64 * 2);
  bf16*  rbf  = (bf16*)take((size_t)256 * ED * 2);
  bf16*  r2bf = (bf16*)take((size_t)128 * ED * 2);
  float* xm   = (float*)take((size_t)NB * ED * 4);

  // Arena W: pre-layer weights; setup overlay = wrnet + wpatch
  char* arenaW = take((size_t)(2304 * 768 + 768 * 768 + 3072 * 768 + 768 * 3072) * 2);
  bf16* wq = (bf16*)arenaW;
  bf16* wo = wq + (size_t)2304 * 768;
  bf16* w1 = wo + (size_t)768 * 768;
  bf16* w2 = w1 + (size_t)3072 * 768;
  bf16* wrnet  = (bf16*)arenaW;
  bf16* wpatch = wrnet + (size_t)LTOT * 768 * 768;

  // Arena Q: overlays: A0 (setup im2col), vT (pre-attn), P (split-K partials, pre 2x / short 4x)
  char* arenaQ = take((size_t)2 * MM1 * ED * 4);   // 38.5 MB covers all overlays
  bf16*  A0 = (bf16*)arenaQ;
  bf16*  vT = (bf16*)arenaQ;
  float* P  = (float*)arenaQ;

  // Arena H: heads(bf16); setup overlay = rkall1+rkall2
  char* arenaH = take((size_t)MM1 * 3 * ED * 2);
  bf16*  headsb = (bf16*)arenaH;
  float* rkall1 = (float*)arenaH;
  float* rkall2 = (float*)(arenaH + (size_t)256 * 1536 * 4);

  // Arena S: {avb, hb}
  char* arenaS = take((size_t)MM1 * ED * 2 + (size_t)MM1 * FFD * 2);
  bf16*  avb  = (bf16*)arenaS;
  bf16*  hb   = (bf16*)(arenaS + (size_t)MM1 * ED * 2);

  if (off > ws_size) return;

  // ---- setup ----
  k_posemb<<<dim3(256), dim3(768), 0, stream>>>(rbf, TT1);
  k_posemb<<<dim3(128), dim3(768), 0, stream>>>(r2bf, TT2);
  k_cvt<<<dim3(1024), dim3(256), 0, stream>>>(rnet_w, wrnet, (long)LTOT * 768 * 768 / 8);
  k_cvt<<<dim3(288), dim3(256), 0, stream>>>(patch_w, wpatch, (long)768 * 768 / 8);
  k_im2col<<<dim3((MM1 * ED + 255) / 256), dim3(256), 0, stream>>>(in_x, A0);
  k_gemm<2><<<dim3(6, 49, 1), dim3(256), 0, stream>>>(A0, wpatch, patch_b, x, xb, MM1, ED, ED, ED);
  k_gemm<0><<<dim3(12, 2, 1), dim3(256), 0, stream>>>(rbf, wrnet, rnet_b, rkall1, nullptr, 256, 1536, ED, ED);
  k_gemm<0><<<dim3(48, 1, 1), dim3(256), 0, stream>>>(r2bf, wrnet + (size_t)2 * 768 * 768, rnet_b + 2 * 768,
                                                      rkall2, nullptr, 128, 6144, ED, ED);
  k_rkrepack<<<dim3(TPM, 2), dim3(768), 0, stream>>>(rkall1, rkb, TT1, 1536, 0);
  k_rkrepack<<<dim3(48, 8), dim3(768), 0, stream>>>(rkall2, rkb, TT2, 6144, 2);

  // ---- transformer layers ----
  for (int l = 0; l < LTOT; ++l) {
    const bool pre = (l < 2);
    const int Mp = pre ? MM1 : MM2;
    const int Mreal = pre ? MM1 : M2R;
    float* xcur = pre ? x : x2;
    bf16* xbcur = pre ? xb : xb2;

    k_cvt4<<<dim3(1024), dim3(256), 0, stream>>>(
        qkv_w + (size_t)l * 2304 * 768, onet_w + (size_t)l * 768 * 768,
        ff1_w + (size_t)l * 3072 * 768, ff2_w + (size_t)l * 768 * 3072,
        wq, wo, w1, w2, 2304 * 768 / 8, 768 * 768 / 8, 3072 * 768 / 8, 768 * 3072 / 8);

    k_gemm<3><<<dim3(18, Mp / 128, 1), dim3(256), 0, stream>>>(xbcur, wq, qkv_b + (size_t)l * 2304,
                                                               nullptr, headsb, Mp, 3 * ED, ED, ED);
    if (pre) {
      k_vrepack<<<dim3(BHN), dim3(256), 0, stream>>>(headsb, vT);
      k_attn_pre<<<dim3(7 * BHN), dim3(256), 0, stream>>>(
          headsb, r_w_bias, r_r_bias, rkb + (size_t)l * NH * TPM * 64, vT, avb);
      // wo: split-K x2 -> fused reduce+residual+LN1
      k_gemm<4><<<dim3(6, Mp / 128, 2), dim3(256), 0, stream>>>(
          avb, wo, nullptr, P, nullptr, Mp, ED, 384, ED);
      k_redk_ln<<<dim3(Mp), dim3(256), 0, stream>>>(P, onet_b + (size_t)l * 768,
                                                    ln1_g + (size_t)l * 768, ln1_b + (size_t)l * 768,
                                                    xcur, xcur, xbcur, 2, (long)Mp * ED, Mreal);
      k_gemm<1><<<dim3(24, Mp / 128, 1), dim3(256), 0, stream>>>(xbcur, w1, ff1_b + (size_t)l * 3072,
                                                                 nullptr, hb, Mp, FFD, ED, ED);
      // ff2: split-K x2 -> fused reduce+residual+LN2
      k_gemm<4><<<dim3(6, Mp / 128, 2), dim3(256), 0, stream>>>(
          hb, w2, nullptr, P, nullptr, Mp, ED, 1536, FFD);
      k_redk_ln<<<dim3(Mp), dim3(256), 0, stream>>>(P, ff2_b + (size_t)l * 768,
                                                    ln2_g + (size_t)l * 768, ln2_b + (size_t)l * 768,
                                                    xcur, xcur, xbcur, 2, (long)Mp * ED, Mreal);
    } else {
      k_attn_short<<<dim3(BHN), dim3(256), 0, stream>>>(
          headsb, r_w_bias, r_r_bias, rkb + (size_t)l * NH * TPM * 64, avb);
      // wo: split-K x2 -> partials -> fused reduce+residual+LN1
      k_gemm<4><<<dim3(6, Mp / 128, 2), dim3(256), 0, stream>>>(avb, wo, nullptr,
                                                                P, nullptr, Mp, ED, 384, ED);
      k_redk_ln<<<dim3(Mp), dim3(256), 0, stream>>>(P, onet_b + (size_t)l * 768,
                                                    ln1_g + (size_t)l * 768, ln1_b + (size_t)l * 768,
                                                    xcur, xcur, xbcur, 2, (long)Mp * ED, Mreal);
      k_gemm<1><<<dim3(24, Mp / 128, 1), dim3(256), 0, stream>>>(xbcur, w1, ff1_b + (size_t)l * 3072,
                                                                 nullptr, hb, Mp, FFD, ED, ED);
      // ff2: split-K x4 -> partials -> fused reduce+residual+LN2
      k_gemm<4><<<dim3(6, Mp / 128, 4), dim3(256), 0, stream>>>(hb, w2, nullptr,
                                                                P, nullptr, Mp, ED, 768, FFD);
      k_redk_ln<<<dim3(Mp), dim3(256), 0, stream>>>(P, ff2_b + (size_t)l * 768,
                                                    ln2_g + (size_t)l * 768, ln2_b + (size_t)l * 768,
                                                    xcur, xcur, xbcur, 4, (long)Mp * ED, Mreal);
    }

    if (l == 1) {
      k_down<<<dim3(MM2), dim3(256), 0, stream>>>(x, null_tok, down_g, down_b, x2, xb2);
    }
  }

  // ---- final: token mean + classifier head (fp32) ----
  k_mean<<<dim3(NB), dim3(256), 0, stream>>>(x2, xm);
  k_head<<<dim3(8000), dim3(256), 0, stream>>>(xm, head_w, head_b, out);
}

// Round 20
// 1326.717 us; speedup vs baseline: 1.0156x; 1.0156x over previous
//
#include <hip/hip_runtime.h>
#include <hip/hip_bf16.h>
#include <math.h>
#include <stdint.h>

// ---------------- types ----------------
typedef __bf16 bf16;
typedef __bf16 bf16x8 __attribute__((ext_vector_type(8)));
typedef float  f32x4  __attribute__((ext_vector_type(4)));

// ---------------- model constants ----------------
#define NB   32        // batch
#define ED   768       // embed dim
#define NH   12        // heads
#define DHD  64        // head dim
#define FFD  3072
#define TT1  196       // pre-stack tokens
#define TT2  41        // short-stack tokens
#define TPM  208       // padded token dim (rk row stride)
#define MM1  6272      // 196*32  (= 49*128)
#define MM2  1408      // padded 41*32=1312 -> 11*128
#define M2R  1312
#define BHN  384       // 32*12
#define LTOT 10
#define SCL  0.125f    // 1/sqrt(64)
#define VTS  224       // vT global col stride (padded tokens)
#define SLP  201       // attn_pre S row stride (odd -> bank-spread), 32*201*4 = 25.1 KB

// ---------------- async global->LDS (16B per lane, wave-uniform LDS base) ----------------
__device__ __forceinline__ void gload_lds16(const bf16* g, bf16* l) {
  __builtin_amdgcn_global_load_lds(
      (__attribute__((address_space(1))) void*)(uintptr_t)g,
      (__attribute__((address_space(3))) void*)(uint32_t)(uintptr_t)l,
      16, 0, 0);
}

// ---------------- helpers ----------------
__device__ __forceinline__ float block_sum(float v, float* red, int tid) {
#pragma unroll
  for (int o = 32; o; o >>= 1) v += __shfl_xor(v, o);
  if ((tid & 63) == 0) red[tid >> 6] = v;
  __syncthreads();
  float t = red[0] + red[1] + red[2] + red[3];
  __syncthreads();
  return t;
}

// tanh-form GELU: |err| vs exact erf-GELU ~3e-4, far under the 2.17e-2 threshold.
__device__ __forceinline__ float gelu_f(float v) {
  const float u = v * (0.7978845608f + 0.0356774081f * v * v);
  const float t = 1.0f - 2.0f / (__expf(2.0f * u) + 1.0f);
  return 0.5f * v * (1.0f + t);
}

__device__ __forceinline__ bf16x8 cvt8(const float* __restrict__ s) {
  const f32x4 a = *(const f32x4*)s;
  const f32x4 b = *(const f32x4*)(s + 4);
  bf16x8 o;
#pragma unroll
  for (int j = 0; j < 4; ++j) { o[j] = (bf16)a[j]; o[4 + j] = (bf16)b[j]; }
  return o;
}

// ---------------- fp32 -> bf16 converters (vectorized, n % 8 == 0) ----------------
__global__ void k_cvt(const float* __restrict__ s, bf16* __restrict__ d, long n8) {
  for (long i = (long)blockIdx.x * 256 + threadIdx.x; i < n8; i += (long)gridDim.x * 256)
    *(bf16x8*)&d[i * 8] = cvt8(&s[i * 8]);
}

__global__ void k_cvt4(const float* __restrict__ a, const float* __restrict__ b,
                       const float* __restrict__ c, const float* __restrict__ d,
                       bf16* __restrict__ oa, bf16* __restrict__ ob,
                       bf16* __restrict__ oc, bf16* __restrict__ od,
                       int na8, int nb8, int nc8, int nd8) {
  const long tot = (long)na8 + nb8 + nc8 + nd8;
  for (long i = (long)blockIdx.x * 256 + threadIdx.x; i < tot; i += (long)gridDim.x * 256) {
    if (i < na8) *(bf16x8*)&oa[i * 8] = cvt8(&a[i * 8]);
    else if (i < (long)na8 + nb8) { const long j = i - na8; *(bf16x8*)&ob[j * 8] = cvt8(&b[j * 8]); }
    else if (i < (long)na8 + nb8 + nc8) { const long j = i - na8 - nb8; *(bf16x8*)&oc[j * 8] = cvt8(&c[j * 8]); }
    else { const long j = i - na8 - nb8 - nc8; *(bf16x8*)&od[j * 8] = cvt8(&d[j * 8]); }
  }
}

// ---------------- sinusoidal pos emb (descending pos), bf16 out ----------------
__global__ void k_posemb(bf16* __restrict__ out, int T) {
  const int t = blockIdx.x, c = threadIdx.x;   // block = 768
  float v = 0.0f;
  if (t < T) {
    const float pos = (float)(T - 1 - t);
    const int ci = (c < 384) ? c : c - 384;
    const float invf = expf(-(float)ci * (9.210340371976184f / 384.0f)); // ln(10000)
    const float a = pos * invf;
    v = (c < 384) ? sinf(a) : cosf(a);
  }
  out[(long)t * ED + c] = (bf16)v;
}

// ---------------- im2col for patch embed: A0[t*32+b][c*256+i*16+j] ----------------
__global__ void k_im2col(const float* __restrict__ x, bf16* __restrict__ A0) {
  const long idx = (long)blockIdx.x * 256 + threadIdx.x;
  if (idx >= (long)MM1 * ED) return;
  const int row = (int)(idx / ED), k = (int)(idx % ED);
  const int t = row >> 5, b = row & 31;
  const int c = k >> 8, rem = k & 255, i = rem >> 4, j = rem & 15;
  const int py = t / 14, px = t % 14;
  A0[idx] = (bf16)x[((long)(b * 3 + c) * 224 + (py * 16 + i)) * 224 + px * 16 + j];
}

// ---------------- GEMM: C[m,n] = sum_k A[m,k]*B[n,k] + bias[n] ----------------
// 128x128 tile, BK=32, 4 waves, 3-buffer counted-vmcnt pipeline (T3+T4).
// Bijective XCD-chunked remap of the ROW-MAJOR flat tile index (m204).
// EPI: 0=fp32; 1=GELU->bf16; 2=fp32+bf16; 3=bf16; 4=fp32 partial (split-K).
template <int EPI>
__global__ __launch_bounds__(256) void k_gemm(const bf16* __restrict__ A, const bf16* __restrict__ Bw,
                                              const float* __restrict__ bias,
                                              float* __restrict__ Cf, bf16* __restrict__ Cb,
                                              int M, int N, int K, int LDK) {
  __shared__ __align__(16) bf16 As[3][128 * 32];
  __shared__ __align__(16) bf16 Bs[3][128 * 32];
  const int tid = threadIdx.x;
  const int l = tid & 63, w = tid >> 6;
  const int wr = w >> 1, wc = w & 1;

  // XCD-chunked bijective remap (row-major flat; consecutive logicals share A panel)
  const int gx = gridDim.x;
  const int nwg = gx * gridDim.y;
  const int dph = blockIdx.y * gx + blockIdx.x;   // physical dispatch id (x fastest)
  const int xcd = dph & 7, idx = dph >> 3;
  const int qq = nwg >> 3, rr = nwg & 7;
  const int logical = (xcd < rr ? xcd * (qq + 1) : rr * (qq + 1) + (xcd - rr) * qq) + idx;
  const int by = logical / gx;
  const int m0 = by * 128, n0 = (logical - by * gx) * 128;

  const long koff = (long)blockIdx.z * K;
  const int srow = l >> 2;
  const int scol = ((l & 3) ^ ((l >> 3) & 3)) * 8;
  f32x4 acc[4][4] = {};
  const int nt = K >> 5;

  auto stage = [&](int t, int b) {
    const int kt = t << 5;
#pragma unroll
    for (int p = 0; p < 2; ++p) {
      const int rbase = w * 32 + p * 16;
      gload_lds16(&A[(long)(m0 + rbase + srow) * LDK + koff + kt + scol], &As[b][rbase * 32]);
      gload_lds16(&Bw[(long)(n0 + rbase + srow) * LDK + koff + kt + scol], &Bs[b][rbase * 32]);
    }
  };

  stage(0, 0);
  stage(1, 1);

  int cur = 0;
  for (int t = 0; t < nt; ++t) {
    if (t + 2 < nt) {
      stage(t + 2, cur == 0 ? 2 : cur - 1);
      asm volatile("s_waitcnt vmcnt(8)" ::: "memory");
    } else if (t + 1 < nt) {
      asm volatile("s_waitcnt vmcnt(4)" ::: "memory");
    } else {
      asm volatile("s_waitcnt vmcnt(0)" ::: "memory");
    }
    __builtin_amdgcn_s_barrier();
    {
      bf16x8 af[4], bg[4];
      const int ub = l >> 4;
#pragma unroll
      for (int m = 0; m < 4; ++m) {
        const int row = wr * 64 + m * 16 + (l & 15);
        af[m] = *(const bf16x8*)&As[cur][row * 32 + (ub ^ ((row >> 1) & 3)) * 8];
      }
#pragma unroll
      for (int n = 0; n < 4; ++n) {
        const int row = wc * 64 + n * 16 + (l & 15);
        bg[n] = *(const bf16x8*)&Bs[cur][row * 32 + (ub ^ ((row >> 1) & 3)) * 8];
      }
#pragma unroll
      for (int m = 0; m < 4; ++m)
#pragma unroll
        for (int n = 0; n < 4; ++n)
          acc[m][n] = __builtin_amdgcn_mfma_f32_16x16x32_bf16(af[m], bg[n], acc[m][n], 0, 0, 0);
    }
    asm volatile("s_waitcnt lgkmcnt(0)" ::: "memory");
    __builtin_amdgcn_s_barrier();
    cur = (cur == 2) ? 0 : cur + 1;
  }

  const long pbase = (EPI == 4) ? (long)blockIdx.z * M * N : 0;
#pragma unroll
  for (int m = 0; m < 4; ++m) {
    const int row = m0 + wr * 64 + m * 16 + 4 * (l >> 4);
#pragma unroll
    for (int n = 0; n < 4; ++n) {
      const int col = n0 + wc * 64 + n * 16 + (l & 15);
      const float bv = (EPI == 4) ? 0.0f : bias[col];
#pragma unroll
      for (int r = 0; r < 4; ++r) {
        const float v = acc[m][n][r] + bv;
        const long off = (long)(row + r) * N + col;
        if (EPI == 0) {
          Cf[off] = v;
        } else if (EPI == 1) {
          Cb[off] = (bf16)gelu_f(v);
        } else if (EPI == 2) {
          Cf[off] = v;
          Cb[off] = (bf16)v;
        } else if (EPI == 3) {
          Cb[off] = (bf16)v;
        } else {
          Cf[pbase + off] = v;
        }
      }
    }
  }
}

// ---------------- split-K reduce + bias + residual + LayerNorm (short layers) ----------------
__global__ __launch_bounds__(256) void k_redk_ln(const float* __restrict__ P, const float* __restrict__ bias,
                                                 const float* __restrict__ g, const float* __restrict__ bb,
                                                 const float* __restrict__ xin,
                                                 float* __restrict__ xo, bf16* __restrict__ xbo,
                                                 int KS, long MN, int Mreal) {
  const int row = blockIdx.x, tid = threadIdx.x;
  const long base = (long)row * ED;
  __shared__ float red[4];
  if (row >= Mreal) {
#pragma unroll
    for (int e = 0; e < 3; ++e) { xo[base + tid + e * 256] = 0.0f; xbo[base + tid + e * 256] = (bf16)0.0f; }
    return;
  }
  float v[3];
#pragma unroll
  for (int e = 0; e < 3; ++e) {
    const int c = tid + e * 256;
    float a = bias[c] + xin[base + c];
    for (int ks = 0; ks < KS; ++ks) a += P[(long)ks * MN + base + c];
    v[e] = a;
  }
  const float mean = block_sum(v[0] + v[1] + v[2], red, tid) * (1.0f / ED);
  float sq = 0.0f;
#pragma unroll
  for (int e = 0; e < 3; ++e) { const float dd = v[e] - mean; sq += dd * dd; }
  const float var = block_sum(sq, red, tid) * (1.0f / ED);
  const float rs = rsqrtf(var + 1e-5f);
#pragma unroll
  for (int e = 0; e < 3; ++e) {
    const int c = tid + e * 256;
    const float o = (v[e] - mean) * rs * g[c] + bb[c];
    xo[base + c] = o;
    xbo[base + c] = (bf16)o;
  }
}

// ---------------- V repack (pre layers): heads V -> global vT[bh][64][VTS] ----------------
__global__ __launch_bounds__(256) void k_vrepack(const bf16* __restrict__ heads, bf16* __restrict__ vT) {
  const int bh = blockIdx.x;
  const int b = bh / NH, n = bh % NH;
  const int tid = threadIdx.x;
  __shared__ __align__(16) bf16 vTl[64 * 232];
  for (int task = tid; task < 224 * 8; task += 256) {
    const int j = task >> 3, c8 = (task & 7) * 8;
    bf16x8 vv = {};
    if (j < TT1) vv = *(const bf16x8*)&heads[((long)(j * NB + b)) * (3 * ED) + 2 * ED + n * 64 + c8];
#pragma unroll
    for (int e = 0; e < 8; ++e) {
      const int d = c8 + e;
      vTl[d * 232 + (j ^ (((d >> 3) & 3) << 3))] = vv[e];
    }
  }
  __syncthreads();
  bf16* dst = vT + (long)bh * 64 * VTS;
  for (int task = tid; task < 64 * 28; task += 256) {
    const int d = task / 28, u = task % 28;
    const int j0 = u * 8;
    const int x = ((d >> 3) & 3) << 3;
    *(bf16x8*)&dst[d * VTS + j0] = *(const bf16x8*)&vTl[d * 232 + (j0 ^ x)];
  }
}

// ---------------- fused PRE-stack attention: 1-D grid 2688 = 8 XCD groups x 336 ----------------
// Sl stride 201 (odd, bank-spread); probl overlays Sl (barrier-separated aliasing).
// LDS ~26.9 KB -> 6 blocks/CU. Div-free rel-shift scatter (s = a+b+1).
__global__ __launch_bounds__(256) void k_attn_pre(
    const bf16* __restrict__ heads, const float* __restrict__ rwb, const float* __restrict__ rrb,
    const bf16* __restrict__ rkb_l, const bf16* __restrict__ vT, bf16* __restrict__ avb) {
  const int dsp = blockIdx.x;
  const int logical = (dsp & 7) * 336 + (dsp >> 3);
  const int bh = logical / 7;
  const int r0 = (logical - bh * 7) * 32;
  const int b = bh / NH, n = bh % NH;
  const int tid = threadIdx.x;
  const int l = tid & 63, w = tid >> 6;
  const int fr = l & 15;
  const int fc = 8 * (l >> 4);
  __shared__ __align__(16) char smem[32 * SLP * 4];   // Sl (fp32) overlaid with probl (bf16)
  float* Sl = (float*)smem;
  bf16* probl = (bf16*)smem;                          // [32][232] bf16 = 14.8 KB < 25.1 KB
  __shared__ float red8[256];
  __shared__ float rstat[32];

  // ---- phase 1: AC ----
  {
    const int ti = w & 1;
    const int ar = r0 + ti * 16 + fr;
    bf16x8 qa0 = {}, qa1 = {};
    if (ar < TT1) {
      const bf16* qp = &heads[((long)(ar * NB + b)) * (3 * ED) + n * 64];
      qa0 = *(const bf16x8*)(qp + fc);
      qa1 = *(const bf16x8*)(qp + 32 + fc);
    }
    bf16x8 q0, q1;
#pragma unroll
    for (int e = 0; e < 8; ++e) {
      q0[e] = (bf16)((float)qa0[e] + rwb[n * 64 + fc + e]);
      q1[e] = (bf16)((float)qa1[e] + rwb[n * 64 + 32 + fc + e]);
    }
    auto ldk = [&](int tj, bf16x8& k0, bf16x8& k1) {
      const int br = tj * 16 + fr;
      k0 = bf16x8{}; k1 = bf16x8{};
      if (br < TT1) {
        const bf16* kp = &heads[((long)(br * NB + b)) * (3 * ED) + ED + n * 64];
        k0 = *(const bf16x8*)(kp + fc);
        k1 = *(const bf16x8*)(kp + 32 + fc);
      }
    };
    bf16x8 k0, k1, nk0, nk1;
    const int tj0 = w >> 1;
    ldk(tj0, k0, k1);
    for (int tj = tj0; tj < 13; tj += 2) {
      if (tj + 2 < 13) ldk(tj + 2, nk0, nk1);
      f32x4 c = {};
      c = __builtin_amdgcn_mfma_f32_16x16x32_bf16(q0, k0, c, 0, 0, 0);
      c = __builtin_amdgcn_mfma_f32_16x16x32_bf16(q1, k1, c, 0, 0, 0);
      const int scol = tj * 16 + fr;
      const int srb = ti * 16 + 4 * (l >> 4);
#pragma unroll
      for (int r = 0; r < 4; ++r) Sl[(srb + r) * SLP + scol] = SCL * c[r];
      k0 = nk0; k1 = nk1;
    }
  }
  __syncthreads();

  // ---- phase 2: BD with div-free scatter ----
  {
    bf16x8 qr0[3], qr1[3];
#pragma unroll
    for (int ta = 0; ta < 3; ++ta) {
      const int ar = r0 + ta * 16 + fr;
      bf16x8 qa0 = {}, qa1 = {};
      if (ar < TT1) {
        const bf16* qp = &heads[((long)(ar * NB + b)) * (3 * ED) + n * 64];
        qa0 = *(const bf16x8*)(qp + fc);
        qa1 = *(const bf16x8*)(qp + 32 + fc);
      }
#pragma unroll
      for (int e = 0; e < 8; ++e) {
        qr0[ta][e] = (bf16)((float)qa0[e] + rrb[n * 64 + fc + e]);
        qr1[ta][e] = (bf16)((float)qa1[e] + rrb[n * 64 + 32 + fc + e]);
      }
    }
    auto ldr = [&](int tb, bf16x8& g0, bf16x8& g1) {
      const int br = tb * 16 + fr;
      const bf16* rp = &rkb_l[((long)n * TPM + br) * 64];
      g0 = *(const bf16x8*)(rp + fc);
      g1 = *(const bf16x8*)(rp + 32 + fc);
    };
    bf16x8 g0, g1, ng0, ng1;
    if (w < 13) ldr(w, g0, g1);
    for (int tb = w; tb < 13; tb += 4) {
      if (tb + 4 < 13) ldr(tb + 4, ng0, ng1);
#pragma unroll
      for (int ta = 0; ta < 3; ++ta) {
        f32x4 c = {};
        c = __builtin_amdgcn_mfma_f32_16x16x32_bf16(qr0[ta], g0, c, 0, 0, 0);
        c = __builtin_amdgcn_mfma_f32_16x16x32_bf16(qr1[ta], g1, c, 0, 0, 0);
        const int bcol = tb * 16 + fr;
        const int ab = r0 + ta * 16 + 4 * (l >> 4);
#pragma unroll
        for (int r = 0; r < 4; ++r) {
          const int a = ab + r;
          if (a < TT1 && bcol < TT1) {
            const int s = a + bcol + 1;
            const int i = (s < TT1) ? (a - 1) : a;
            const int j = (s < TT1) ? s : (s - TT1);
            const int li = i - r0;
            if (li >= 0 && li < 32) Sl[li * SLP + j] += SCL * c[r];
          }
        }
      }
      g0 = ng0; g1 = ng1;
    }
  }
  __syncthreads();

  // ---- phase 3: row softmax (8 threads per row); P staged in regs, then alias write ----
  const int sr = tid & 31, sg = tid >> 5;
  const bool rowok = (r0 + sr) < TT1;
  const int j0 = sg * 25;
  const int j1 = (j0 + 25 < TT1) ? j0 + 25 : TT1;
  float pm = -3.0e38f;
  if (rowok) {
    for (int j = j0; j < j1; ++j) pm = fmaxf(pm, Sl[sr * SLP + j]);
  }
  red8[sr * 8 + sg] = pm;
  __syncthreads();
  if (tid < 32) {
    float m0 = red8[tid * 8];
#pragma unroll
    for (int q = 1; q < 8; ++q) m0 = fmaxf(m0, red8[tid * 8 + q]);
    rstat[tid] = m0;
  }
  __syncthreads();
  const float rm = rstat[sr];
  float ps = 0.0f;
  if (rowok) {
    for (int j = j0; j < j1; ++j) {
      const float e = __expf(Sl[sr * SLP + j] - rm);
      Sl[sr * SLP + j] = e;
      ps += e;
    }
  }
  red8[sr * 8 + sg] = ps;
  __syncthreads();
  if (tid < 32) {
    float s0 = 0.0f;
#pragma unroll
    for (int q = 0; q < 8; ++q) s0 += red8[tid * 8 + q];
    rstat[tid] = (s0 > 0.0f) ? 1.0f / s0 : 0.0f;
  }
  __syncthreads();
  {
    const float inv = rstat[sr];
    const int sx = ((sr >> 3) & 3) << 3;
    bf16 hreg[28];
#pragma unroll
    for (int u = 0; u < 28; ++u) {
      const int j = sg * 28 + u;
      const float v = (rowok && j < TT1) ? Sl[sr * SLP + j] * inv : 0.0f;
      hreg[u] = (bf16)v;
    }
    __syncthreads();   // all Sl reads complete before alias writes
#pragma unroll
    for (int u = 0; u < 28; ++u) {
      const int j = sg * 28 + u;
      probl[sr * 232 + (j ^ sx)] = hreg[u];
    }
  }
  __syncthreads();

  // ---- phase 4: PV (P from aliased LDS, V from global vT) ----
  const bf16* vTg = vT + (long)bh * 64 * VTS;
  for (int tt = w; tt < 8; tt += 4) {
    const int ti = tt & 1, dj = tt >> 1;
    const int prow = ti * 16 + fr;
    const int vrow = dj * 16 + fr;
    const int px = ((prow >> 3) & 3) << 3;
    f32x4 c = {};
#pragma unroll
    for (int kk = 0; kk < 224; kk += 32) {
      const int j0v = kk + fc;
      const bf16x8 pa = *(const bf16x8*)&probl[prow * 232 + (j0v ^ px)];
      const bf16x8 vb = *(const bf16x8*)&vTg[vrow * VTS + j0v];
      c = __builtin_amdgcn_mfma_f32_16x16x32_bf16(pa, vb, c, 0, 0, 0);
    }
    const int d = dj * 16 + fr;
    const int ib = ti * 16 + 4 * (l >> 4);
#pragma unroll
    for (int r = 0; r < 4; ++r) {
      const int gi = r0 + ib + r;
      if (gi < TT1) avb[((long)(gi * NB + b)) * ED + n * 64 + d] = (bf16)c[r];
    }
  }
}

// ---------------- fused short-stack attention: one block per (b,h), T=41 ----------------
__global__ __launch_bounds__(256) void k_attn_short(
    const bf16* __restrict__ heads, const float* __restrict__ rwb, const float* __restrict__ rrb,
    const bf16* __restrict__ rkb_l, bf16* __restrict__ avb) {
  const int bh = blockIdx.x;
  const int b = bh / NH, n = bh % NH;
  const int tid = threadIdx.x;
  const int l = tid & 63, w = tid >> 6;
  const int fr = l & 15, fc = 8 * (l >> 4);
  __shared__ float Sl[48 * 49];
  __shared__ __align__(16) bf16 probl[48 * 72];
  __shared__ __align__(16) bf16 vTl[64 * 72];

  for (int task = tid; task < 64 * 8; task += 256) {
    const int j = task >> 3, c8 = (task & 7) * 8;
    bf16x8 vv = {};
    if (j < TT2) vv = *(const bf16x8*)&heads[((long)(j * NB + b)) * (3 * ED) + 2 * ED + n * 64 + c8];
#pragma unroll
    for (int e = 0; e < 8; ++e) {
      const int d = c8 + e;
      vTl[d * 72 + (j ^ (((d >> 3) & 3) << 3))] = vv[e];
    }
  }

  for (int tt = w; tt < 9; tt += 4) {
    const int ti = tt / 3, tj = tt % 3;
    const int ar = ti * 16 + fr;
    const int br = tj * 16 + fr;
    f32x4 c = {};
#pragma unroll
    for (int kk = 0; kk < 64; kk += 32) {
      const int col = kk + fc;
      bf16x8 qa = {}, kb = {};
      if (ar < 44) qa = *(const bf16x8*)&heads[((long)(ar * NB + b)) * (3 * ED) + n * 64 + col];
      if (br < 44) kb = *(const bf16x8*)&heads[((long)(br * NB + b)) * (3 * ED) + ED + n * 64 + col];
      bf16x8 qq;
#pragma unroll
      for (int e = 0; e < 8; ++e) qq[e] = (bf16)((float)qa[e] + rwb[n * 64 + col + e]);
      c = __builtin_amdgcn_mfma_f32_16x16x32_bf16(qq, kb, c, 0, 0, 0);
    }
    const int scol = tj * 16 + fr;
    const int srb = ti * 16 + 4 * (l >> 4);
#pragma unroll
    for (int r = 0; r < 4; ++r) Sl[(srb + r) * 49 + scol] = SCL * c[r];
  }
  __syncthreads();

  for (int tt = w; tt < 9; tt += 4) {
    const int ti = tt / 3, tj = tt % 3;
    const int ar = ti * 16 + fr;
    const int br = tj * 16 + fr;
    f32x4 c = {};
#pragma unroll
    for (int kk = 0; kk < 64; kk += 32) {
      const int col = kk + fc;
      bf16x8 qa = {};
      if (ar < 44) qa = *(const bf16x8*)&heads[((long)(ar * NB + b)) * (3 * ED) + n * 64 + col];
      const bf16x8 rk = *(const bf16x8*)&rkb_l[((long)n * TPM + br) * 64 + col];
      bf16x8 qq;
#pragma unroll
      for (int e = 0; e < 8; ++e) qq[e] = (bf16)((float)qa[e] + rrb[n * 64 + col + e]);
      c = __builtin_amdgcn_mfma_f32_16x16x32_bf16(qq, rk, c, 0, 0, 0);
    }
    const int bcol = tj * 16 + fr;
    const int ab = ti * 16 + 4 * (l >> 4);
#pragma unroll
    for (int r = 0; r < 4; ++r) {
      const int a = ab + r;
      if (a < TT2 && bcol < TT2) {
        const int s = a + bcol + 1;
        const int i = (s < TT2) ? (a - 1) : a;
        const int j = (s < TT2) ? s : (s - TT2);
        if (i >= 0) Sl[i * 49 + j] += SCL * c[r];
      }
    }
  }
  __syncthreads();

  if (tid < 48) {
    const int i = tid;
    const int ix = ((i >> 3) & 3) << 3;
    if (i < TT2) {
      float mx = -3.0e38f;
      for (int j = 0; j < TT2; ++j) mx = fmaxf(mx, Sl[i * 49 + j]);
      float sm = 0.0f;
      for (int j = 0; j < TT2; ++j) { const float e = expf(Sl[i * 49 + j] - mx); Sl[i * 49 + j] = e; sm += e; }
      const float inv = 1.0f / sm;
      for (int j = 0; j < TT2; ++j) probl[i * 72 + (j ^ ix)] = (bf16)(Sl[i * 49 + j] * inv);
      for (int j = TT2; j < 64; ++j) probl[i * 72 + (j ^ ix)] = (bf16)0.0f;
    } else {
      for (int j = 0; j < 64; ++j) probl[i * 72 + (j ^ ix)] = (bf16)0.0f;
    }
  }
  __syncthreads();

  for (int tt = w; tt < 12; tt += 4) {
    const int ti = tt % 3, dj = tt / 3;
    const int prow = ti * 16 + fr;
    const int vrow = dj * 16 + fr;
    const int px = ((prow >> 3) & 3) << 3;
    const int vx = ((vrow >> 3) & 3) << 3;
    f32x4 c = {};
#pragma unroll
    for (int kk = 0; kk < 64; kk += 32) {
      const int j0 = kk + fc;
      const bf16x8 pa = *(const bf16x8*)&probl[prow * 72 + (j0 ^ px)];
      const bf16x8 vb = *(const bf16x8*)&vTl[vrow * 72 + (j0 ^ vx)];
      c = __builtin_amdgcn_mfma_f32_16x16x32_bf16(pa, vb, c, 0, 0, 0);
    }
    const int d = dj * 16 + fr;
    const int ib = ti * 16 + 4 * (l >> 4);
#pragma unroll
    for (int r = 0; r < 4; ++r) {
      const int i = ib + r;
      if (i < TT2) avb[((long)(i * NB + b)) * ED + n * 64 + d] = (bf16)c[r];
    }
  }
}

// ---------------- rk repack: rkall fp32 [rows][nl*768] -> rkb bf16 [l][n][TPM][64] ----------------
__global__ void k_rkrepack(const float* __restrict__ rkall, bf16* __restrict__ rkb,
                           int T, int Ncols, int l0) {
  const int i = blockIdx.x, z = blockIdx.y, d = threadIdx.x;  // block = 768
  const float v = (i < T) ? rkall[(long)i * Ncols + z * ED + d] : 0.0f;
  const int n = d >> 6, dh = d & 63;
  rkb[(((long)(l0 + z) * NH + n) * TPM + i) * 64 + dh] = (bf16)v;
}

// ---------------- residual + LayerNorm (fp32 master, bf16 copy) ----------------
__global__ __launch_bounds__(256) void k_ln(const float* __restrict__ xin, const float* __restrict__ add,
                                            const float* __restrict__ g, const float* __restrict__ bb,
                                            float* __restrict__ xo, bf16* __restrict__ xbo, int Mreal) {
  const int row = blockIdx.x, tid = threadIdx.x;
  const long base = (long)row * ED;
  __shared__ float red[4];
  if (row >= Mreal) {
#pragma unroll
    for (int e = 0; e < 3; ++e) { xo[base + tid + e * 256] = 0.0f; xbo[base + tid + e * 256] = (bf16)0.0f; }
    return;
  }
  float v[3];
#pragma unroll
  for (int e = 0; e < 3; ++e) v[e] = xin[base + tid + e * 256] + add[base + tid + e * 256];
  const float mean = block_sum(v[0] + v[1] + v[2], red, tid) * (1.0f / ED);
  float sq = 0.0f;
#pragma unroll
  for (int e = 0; e < 3; ++e) { const float dd = v[e] - mean; sq += dd * dd; }
  const float var = block_sum(sq, red, tid) * (1.0f / ED);
  const float rs = rsqrtf(var + 1e-5f);
#pragma unroll
  for (int e = 0; e < 3; ++e) {
    const int c = tid + e * 256;
    const float o = (v[e] - mean) * rs * g[c] + bb[c];
    xo[base + c] = o;
    xbo[base + c] = (bf16)o;
  }
}

// ---------------- downsample: segment-mean pool + null token + LN ----------------
__global__ __launch_bounds__(256) void k_down(const float* __restrict__ x, const float* __restrict__ nullt,
                                              const float* __restrict__ g, const float* __restrict__ bb,
                                              float* __restrict__ xo, bf16* __restrict__ xbo) {
  const int row = blockIdx.x, tid = threadIdx.x;
  const long base = (long)row * ED;
  __shared__ float red[4];
  if (row >= TT2 * NB) {
#pragma unroll
    for (int e = 0; e < 3; ++e) { xo[base + tid + e * 256] = 0.0f; xbo[base + tid + e * 256] = (bf16)0.0f; }
    return;
  }
  const int s = row >> 5, b = row & 31;
  float v[3];
  if (s == 0) {
#pragma unroll
    for (int e = 0; e < 3; ++e) v[e] = nullt[tid + e * 256];
  } else {
    const int seg = s - 1;
    const int t0 = (seg == 0) ? 0 : (5 * seg - 4);
    const int cnt = (seg == 0) ? 1 : 5;
#pragma unroll
    for (int e = 0; e < 3; ++e) {
      float a = 0.0f;
      for (int tt = 0; tt < cnt; ++tt) a += x[((long)((t0 + tt) * NB + b)) * ED + tid + e * 256];
      v[e] = a / (float)cnt;
    }
  }
  const float mean = block_sum(v[0] + v[1] + v[2], red, tid) * (1.0f / ED);
  float sq = 0.0f;
#pragma unroll
  for (int e = 0; e < 3; ++e) { const float dd = v[e] - mean; sq += dd * dd; }
  const float var = block_sum(sq, red, tid) * (1.0f / ED);
  const float rs = rsqrtf(var + 1e-5f);
#pragma unroll
  for (int e = 0; e < 3; ++e) {
    const int c = tid + e * 256;
    const float o = (v[e] - mean) * rs * g[c] + bb[c];
    xo[base + c] = o;
    xbo[base + c] = (bf16)o;
  }
}

// ---------------- final token mean (fp32) ----------------
__global__ __launch_bounds__(256) void k_mean(const float* __restrict__ x2, float* __restrict__ xm) {
  const int b = blockIdx.x, tid = threadIdx.x;
#pragma unroll
  for (int e = 0; e < 3; ++e) {
    const int c = tid + e * 256;
    float a = 0.0f;
    for (int s = 0; s < TT2; ++s) a += x2[((long)(s * NB + b)) * ED + c];
    xm[(long)b * ED + c] = a * (1.0f / TT2);
  }
}

// ---------------- classifier head (fp32 dot, wave per (b,n)) ----------------
__global__ __launch_bounds__(256) void k_head(const float* __restrict__ xm, const float* __restrict__ hw,
                                              const float* __restrict__ hbias, float* __restrict__ out) {
  const int gid = blockIdx.x * 4 + (threadIdx.x >> 6);
  const int l = threadIdx.x & 63;
  if (gid >= NB * 1000) return;
  const int b = gid / 1000, n = gid % 1000;
  const float* xr = xm + (long)b * ED;
  const float* wr = hw + (long)n * ED;
  float a = 0.0f;
#pragma unroll
  for (int e = 0; e < 12; ++e) a += xr[l + 64 * e] * wr[l + 64 * e];
#pragma unroll
  for (int o = 32; o; o >>= 1) a += __shfl_xor(a, o);
  if (l == 0) out[(long)b * 1000 + n] = a + hbias[n];
}

// =======================================================================
extern "C" void kernel_launch(void* const* d_in, const int* in_sizes, int n_in,
                              void* d_out, int out_size, void* d_ws, size_t ws_size,
                              hipStream_t stream) {
  const float* in_x     = (const float*)d_in[0];
  const float* patch_w  = (const float*)d_in[1];
  const float* patch_b  = (const float*)d_in[2];
  const float* r_w_bias = (const float*)d_in[3];
  const float* r_r_bias = (const float*)d_in[4];
  const float* qkv_w    = (const float*)d_in[5];
  const float* qkv_b    = (const float*)d_in[6];
  const float* rnet_w   = (const float*)d_in[7];
  const float* rnet_b   = (const float*)d_in[8];
  const float* onet_w   = (const float*)d_in[9];
  const float* onet_b   = (const float*)d_in[10];
  const float* ln1_g    = (const float*)d_in[11];
  const float* ln1_b    = (const float*)d_in[12];
  const float* ff1_w    = (const float*)d_in[13];
  const float* ff1_b    = (const float*)d_in[14];
  const float* ff2_w    = (const float*)d_in[15];
  const float* ff2_b    = (const float*)d_in[16];
  const float* ln2_g    = (const float*)d_in[17];
  const float* ln2_b    = (const float*)d_in[18];
  const float* null_tok = (const float*)d_in[19];
  const float* down_g   = (const float*)d_in[20];
  const float* down_b   = (const float*)d_in[21];
  const float* head_w   = (const float*)d_in[22];
  const float* head_b   = (const float*)d_in[23];
  float* out = (float*)d_out;

  char* base = (char*)d_ws;
  size_t off = 0;
  auto take = [&](size_t bytes) -> char* {
    char* r = base + off;
    off += (bytes + 255) & ~(size_t)255;
    return r;
  };

  // persistent
  float* x    = (float*)take((size_t)MM1 * ED * 4);
  bf16*  xb   = (bf16*)take((size_t)MM1 * ED * 2);
  float* x2   = (float*)take((size_t)MM2 * ED * 4);
  bf16*  xb2  = (bf16*)take((size_t)MM2 * ED * 2);
  bf16*  rkb  = (bf16*)take((size_t)LTOT * NH * TPM * 64 * 2);
  bf16*  rbf  = (bf16*)take((size_t)256 * ED * 2);
  bf16*  r2bf = (bf16*)take((size_t)128 * ED * 2);
  float* xm   = (float*)take((size_t)NB * ED * 4);

  // Arena W: pre-layer weights; setup overlay = wrnet + wpatch
  char* arenaW = take((size_t)(2304 * 768 + 768 * 768 + 3072 * 768 + 768 * 3072) * 2);
  bf16* wq = (bf16*)arenaW;
  bf16* wo = wq + (size_t)2304 * 768;
  bf16* w1 = wo + (size_t)768 * 768;
  bf16* w2 = w1 + (size_t)3072 * 768;
  bf16* wrnet  = (bf16*)arenaW;
  bf16* wpatch = wrnet + (size_t)LTOT * 768 * 768;

  // Arena Q: overlays: A0 (setup im2col), vT (pre-attn), P (short split-K)
  char* arenaQ = take((size_t)MM1 * ED * 2 + (size_t)4 * MM2 * ED * 4);
  bf16*  A0 = (bf16*)arenaQ;
  bf16*  vT = (bf16*)arenaQ;
  float* P  = (float*)arenaQ;

  // Arena H: heads(bf16); setup overlay = rkall1+rkall2
  char* arenaH = take((size_t)MM1 * 3 * ED * 2);
  bf16*  headsb = (bf16*)arenaH;
  float* rkall1 = (float*)arenaH;
  float* rkall2 = (float*)(arenaH + (size_t)256 * 1536 * 4);

  // Arena S: {avb, gout, hb}
  char* arenaS = take((size_t)MM1 * ED * 2 + (size_t)MM1 * ED * 4 + (size_t)MM1 * FFD * 2);
  bf16*  avb  = (bf16*)arenaS;
  float* gout = (float*)(arenaS + (size_t)MM1 * ED * 2);
  bf16*  hb   = (bf16*)(arenaS + (size_t)MM1 * ED * 2 + (size_t)MM1 * ED * 4);

  if (off > ws_size) return;

  // ---- setup ----
  k_posemb<<<dim3(256), dim3(768), 0, stream>>>(rbf, TT1);
  k_posemb<<<dim3(128), dim3(768), 0, stream>>>(r2bf, TT2);
  k_cvt<<<dim3(1024), dim3(256), 0, stream>>>(rnet_w, wrnet, (long)LTOT * 768 * 768 / 8);
  k_cvt<<<dim3(288), dim3(256), 0, stream>>>(patch_w, wpatch, (long)768 * 768 / 8);
  k_im2col<<<dim3((MM1 * ED + 255) / 256), dim3(256), 0, stream>>>(in_x, A0);
  k_gemm<2><<<dim3(6, 49, 1), dim3(256), 0, stream>>>(A0, wpatch, patch_b, x, xb, MM1, ED, ED, ED);
  k_gemm<0><<<dim3(12, 2, 1), dim3(256), 0, stream>>>(rbf, wrnet, rnet_b, rkall1, nullptr, 256, 1536, ED, ED);
  k_gemm<0><<<dim3(48, 1, 1), dim3(256), 0, stream>>>(r2bf, wrnet + (size_t)2 * 768 * 768, rnet_b + 2 * 768,
                                                      rkall2, nullptr, 128, 6144, ED, ED);
  k_rkrepack<<<dim3(TPM, 2), dim3(768), 0, stream>>>(rkall1, rkb, TT1, 1536, 0);
  k_rkrepack<<<dim3(48, 8), dim3(768), 0, stream>>>(rkall2, rkb, TT2, 6144, 2);

  // ---- transformer layers ----
  for (int l = 0; l < LTOT; ++l) {
    const bool pre = (l < 2);
    const int Mp = pre ? MM1 : MM2;
    const int Mreal = pre ? MM1 : M2R;
    float* xcur = pre ? x : x2;
    bf16* xbcur = pre ? xb : xb2;

    k_cvt4<<<dim3(1024), dim3(256), 0, stream>>>(
        qkv_w + (size_t)l * 2304 * 768, onet_w + (size_t)l * 768 * 768,
        ff1_w + (size_t)l * 3072 * 768, ff2_w + (size_t)l * 768 * 3072,
        wq, wo, w1, w2, 2304 * 768 / 8, 768 * 768 / 8, 3072 * 768 / 8, 768 * 3072 / 8);

    k_gemm<3><<<dim3(18, Mp / 128, 1), dim3(256), 0, stream>>>(xbcur, wq, qkv_b + (size_t)l * 2304,
                                                               nullptr, headsb, Mp, 3 * ED, ED, ED);
    if (pre) {
      k_vrepack<<<dim3(BHN), dim3(256), 0, stream>>>(headsb, vT);
      k_attn_pre<<<dim3(7 * BHN), dim3(256), 0, stream>>>(
          headsb, r_w_bias, r_r_bias, rkb + (size_t)l * NH * TPM * 64, vT, avb);
      k_gemm<0><<<dim3(6, Mp / 128, 1), dim3(256), 0, stream>>>(avb, wo, onet_b + (size_t)l * 768,
                                                                gout, nullptr, Mp, ED, ED, ED);
      k_ln<<<dim3(Mp), dim3(256), 0, stream>>>(xcur, gout, ln1_g + (size_t)l * 768, ln1_b + (size_t)l * 768,
                                               xcur, xbcur, Mreal);
      k_gemm<1><<<dim3(24, Mp / 128, 1), dim3(256), 0, stream>>>(xbcur, w1, ff1_b + (size_t)l * 3072,
                                                                 nullptr, hb, Mp, FFD, ED, ED);
      k_gemm<0><<<dim3(6, Mp / 128, 1), dim3(256), 0, stream>>>(hb, w2, ff2_b + (size_t)l * 768,
                                                                gout, nullptr, Mp, ED, FFD, FFD);
      k_ln<<<dim3(Mp), dim3(256), 0, stream>>>(xcur, gout, ln2_g + (size_t)l * 768, ln2_b + (size_t)l * 768,
                                               xcur, xbcur, Mreal);
    } else {
      k_attn_short<<<dim3(BHN), dim3(256), 0, stream>>>(
          headsb, r_w_bias, r_r_bias, rkb + (size_t)l * NH * TPM * 64, avb);
      // wo: split-K x2 -> partials -> fused reduce+residual+LN1
      k_gemm<4><<<dim3(6, Mp / 128, 2), dim3(256), 0, stream>>>(avb, wo, nullptr,
                                                                P, nullptr, Mp, ED, 384, ED);
      k_redk_ln<<<dim3(Mp), dim3(256), 0, stream>>>(P, onet_b + (size_t)l * 768,
                                                    ln1_g + (size_t)l * 768, ln1_b + (size_t)l * 768,
                                                    xcur, xcur, xbcur, 2, (long)Mp * ED, Mreal);
      k_gemm<1><<<dim3(24, Mp / 128, 1), dim3(256), 0, stream>>>(xbcur, w1, ff1_b + (size_t)l * 3072,
                                                                 nullptr, hb, Mp, FFD, ED, ED);
      // ff2: split-K x4 -> partials -> fused reduce+residual+LN2
      k_gemm<4><<<dim3(6, Mp / 128, 4), dim3(256), 0, stream>>>(hb, w2, nullptr,
                                                                P, nullptr, Mp, ED, 768, FFD);
      k_redk_ln<<<dim3(Mp), dim3(256), 0, stream>>>(P, ff2_b + (size_t)l * 768,
                                                    ln2_g + (size_t)l * 768, ln2_b + (size_t)l * 768,
                                                    xcur, xcur, xbcur, 4, (long)Mp * ED, Mreal);
    }

    if (l == 1) {
      k_down<<<dim3(MM2), dim3(256), 0, stream>>>(x, null_tok, down_g, down_b, x2, xb2);
    }
  }

  // ---- final: token mean + classifier head (fp32) ----
  k_mean<<<dim3(NB), dim3(256), 0, stream>>>(x2, xm);
  k_head<<<dim3(8000), dim3(256), 0, stream>>>(xm, head_w, head_b, out);
}

// Round 21
// 1322.374 us; speedup vs baseline: 1.0189x; 1.0033x over previous
//
#include <hip/hip_runtime.h>
#include <hip/hip_bf16.h>
#include <math.h>
#include <stdint.h>

// ---------------- types ----------------
typedef __bf16 bf16;
typedef __bf16 bf16x8 __attribute__((ext_vector_type(8)));
typedef float  f32x4  __attribute__((ext_vector_type(4)));

// ---------------- model constants ----------------
#define NB   32        // batch
#define ED   768       // embed dim
#define NH   12        // heads
#define DHD  64        // head dim
#define FFD  3072
#define TT1  196       // pre-stack tokens
#define TT2  41        // short-stack tokens
#define TPM  208       // padded token dim (rk row stride)
#define MM1  6272      // 196*32  (= 49*128)
#define MM2  1408      // padded 41*32=1312 -> 11*128
#define M2R  1312
#define BHN  384       // 32*12
#define LTOT 10
#define SCL  0.125f    // 1/sqrt(64)
#define VTS  224       // vT global col stride (padded tokens)
#define SLP  201       // attn_pre S row stride (odd -> bank-spread), 32*201*4 = 25.1 KB

// ---------------- async global->LDS (16B per lane, wave-uniform LDS base) ----------------
__device__ __forceinline__ void gload_lds16(const bf16* g, bf16* l) {
  __builtin_amdgcn_global_load_lds(
      (__attribute__((address_space(1))) void*)(uintptr_t)g,
      (__attribute__((address_space(3))) void*)(uint32_t)(uintptr_t)l,
      16, 0, 0);
}

// ---------------- helpers ----------------
__device__ __forceinline__ float block_sum(float v, float* red, int tid) {
#pragma unroll
  for (int o = 32; o; o >>= 1) v += __shfl_xor(v, o);
  if ((tid & 63) == 0) red[tid >> 6] = v;
  __syncthreads();
  float t = red[0] + red[1] + red[2] + red[3];
  __syncthreads();
  return t;
}

// tanh-form GELU: |err| vs exact erf-GELU ~3e-4, far under the 2.17e-2 threshold.
__device__ __forceinline__ float gelu_f(float v) {
  const float u = v * (0.7978845608f + 0.0356774081f * v * v);
  const float t = 1.0f - 2.0f / (__expf(2.0f * u) + 1.0f);
  return 0.5f * v * (1.0f + t);
}

// r21: nontemporal fp32 loads — weights are read-once streams; keep bf16 stores cached
// (the GEMMs re-read them from L2 shortly after).
__device__ __forceinline__ bf16x8 cvt8(const float* __restrict__ s) {
  const f32x4 a = __builtin_nontemporal_load((const f32x4*)s);
  const f32x4 b = __builtin_nontemporal_load((const f32x4*)(s + 4));
  bf16x8 o;
#pragma unroll
  for (int j = 0; j < 4; ++j) { o[j] = (bf16)a[j]; o[4 + j] = (bf16)b[j]; }
  return o;
}

// ---------------- fp32 -> bf16 converters (vectorized, n % 8 == 0) ----------------
__global__ void k_cvt(const float* __restrict__ s, bf16* __restrict__ d, long n8) {
  for (long i = (long)blockIdx.x * 256 + threadIdx.x; i < n8; i += (long)gridDim.x * 256)
    *(bf16x8*)&d[i * 8] = cvt8(&s[i * 8]);
}

__global__ void k_cvt4(const float* __restrict__ a, const float* __restrict__ b,
                       const float* __restrict__ c, const float* __restrict__ d,
                       bf16* __restrict__ oa, bf16* __restrict__ ob,
                       bf16* __restrict__ oc, bf16* __restrict__ od,
                       int na8, int nb8, int nc8, int nd8) {
  const long tot = (long)na8 + nb8 + nc8 + nd8;
  for (long i = (long)blockIdx.x * 256 + threadIdx.x; i < tot; i += (long)gridDim.x * 256) {
    if (i < na8) *(bf16x8*)&oa[i * 8] = cvt8(&a[i * 8]);
    else if (i < (long)na8 + nb8) { const long j = i - na8; *(bf16x8*)&ob[j * 8] = cvt8(&b[j * 8]); }
    else if (i < (long)na8 + nb8 + nc8) { const long j = i - na8 - nb8; *(bf16x8*)&oc[j * 8] = cvt8(&c[j * 8]); }
    else { const long j = i - na8 - nb8 - nc8; *(bf16x8*)&od[j * 8] = cvt8(&d[j * 8]); }
  }
}

// ---------------- sinusoidal pos emb (descending pos), bf16 out ----------------
__global__ void k_posemb(bf16* __restrict__ out, int T) {
  const int t = blockIdx.x, c = threadIdx.x;   // block = 768
  float v = 0.0f;
  if (t < T) {
    const float pos = (float)(T - 1 - t);
    const int ci = (c < 384) ? c : c - 384;
    const float invf = expf(-(float)ci * (9.210340371976184f / 384.0f)); // ln(10000)
    const float a = pos * invf;
    v = (c < 384) ? sinf(a) : cosf(a);
  }
  out[(long)t * ED + c] = (bf16)v;
}

// ---------------- im2col for patch embed: A0[t*32+b][c*256+i*16+j] ----------------
__global__ void k_im2col(const float* __restrict__ x, bf16* __restrict__ A0) {
  const long idx = (long)blockIdx.x * 256 + threadIdx.x;
  if (idx >= (long)MM1 * ED) return;
  const int row = (int)(idx / ED), k = (int)(idx % ED);
  const int t = row >> 5, b = row & 31;
  const int c = k >> 8, rem = k & 255, i = rem >> 4, j = rem & 15;
  const int py = t / 14, px = t % 14;
  A0[idx] = (bf16)x[((long)(b * 3 + c) * 224 + (py * 16 + i)) * 224 + px * 16 + j];
}

// ---------------- GEMM: C[m,n] = sum_k A[m,k]*B[n,k] + bias[n] ----------------
// 128x128 tile, BK=32, 4 waves, 3-buffer counted-vmcnt pipeline (T3+T4).
// Bijective XCD-chunked remap of the ROW-MAJOR flat tile index (m204).
// EPI: 0=fp32; 1=GELU->bf16; 2=fp32+bf16; 3=bf16; 4=fp32 partial (split-K).
template <int EPI>
__global__ __launch_bounds__(256) void k_gemm(const bf16* __restrict__ A, const bf16* __restrict__ Bw,
                                              const float* __restrict__ bias,
                                              float* __restrict__ Cf, bf16* __restrict__ Cb,
                                              int M, int N, int K, int LDK) {
  __shared__ __align__(16) bf16 As[3][128 * 32];
  __shared__ __align__(16) bf16 Bs[3][128 * 32];
  const int tid = threadIdx.x;
  const int l = tid & 63, w = tid >> 6;
  const int wr = w >> 1, wc = w & 1;

  // XCD-chunked bijective remap (row-major flat; consecutive logicals share A panel)
  const int gx = gridDim.x;
  const int nwg = gx * gridDim.y;
  const int dph = blockIdx.y * gx + blockIdx.x;   // physical dispatch id (x fastest)
  const int xcd = dph & 7, idx = dph >> 3;
  const int qq = nwg >> 3, rr = nwg & 7;
  const int logical = (xcd < rr ? xcd * (qq + 1) : rr * (qq + 1) + (xcd - rr) * qq) + idx;
  const int by = logical / gx;
  const int m0 = by * 128, n0 = (logical - by * gx) * 128;

  const long koff = (long)blockIdx.z * K;
  const int srow = l >> 2;
  const int scol = ((l & 3) ^ ((l >> 3) & 3)) * 8;
  f32x4 acc[4][4] = {};
  const int nt = K >> 5;

  auto stage = [&](int t, int b) {
    const int kt = t << 5;
#pragma unroll
    for (int p = 0; p < 2; ++p) {
      const int rbase = w * 32 + p * 16;
      gload_lds16(&A[(long)(m0 + rbase + srow) * LDK + koff + kt + scol], &As[b][rbase * 32]);
      gload_lds16(&Bw[(long)(n0 + rbase + srow) * LDK + koff + kt + scol], &Bs[b][rbase * 32]);
    }
  };

  stage(0, 0);
  stage(1, 1);

  int cur = 0;
  for (int t = 0; t < nt; ++t) {
    if (t + 2 < nt) {
      stage(t + 2, cur == 0 ? 2 : cur - 1);
      asm volatile("s_waitcnt vmcnt(8)" ::: "memory");
    } else if (t + 1 < nt) {
      asm volatile("s_waitcnt vmcnt(4)" ::: "memory");
    } else {
      asm volatile("s_waitcnt vmcnt(0)" ::: "memory");
    }
    __builtin_amdgcn_s_barrier();
    {
      bf16x8 af[4], bg[4];
      const int ub = l >> 4;
#pragma unroll
      for (int m = 0; m < 4; ++m) {
        const int row = wr * 64 + m * 16 + (l & 15);
        af[m] = *(const bf16x8*)&As[cur][row * 32 + (ub ^ ((row >> 1) & 3)) * 8];
      }
#pragma unroll
      for (int n = 0; n < 4; ++n) {
        const int row = wc * 64 + n * 16 + (l & 15);
        bg[n] = *(const bf16x8*)&Bs[cur][row * 32 + (ub ^ ((row >> 1) & 3)) * 8];
      }
#pragma unroll
      for (int m = 0; m < 4; ++m)
#pragma unroll
        for (int n = 0; n < 4; ++n)
          acc[m][n] = __builtin_amdgcn_mfma_f32_16x16x32_bf16(af[m], bg[n], acc[m][n], 0, 0, 0);
    }
    asm volatile("s_waitcnt lgkmcnt(0)" ::: "memory");
    __builtin_amdgcn_s_barrier();
    cur = (cur == 2) ? 0 : cur + 1;
  }

  const long pbase = (EPI == 4) ? (long)blockIdx.z * M * N : 0;
#pragma unroll
  for (int m = 0; m < 4; ++m) {
    const int row = m0 + wr * 64 + m * 16 + 4 * (l >> 4);
#pragma unroll
    for (int n = 0; n < 4; ++n) {
      const int col = n0 + wc * 64 + n * 16 + (l & 15);
      const float bv = (EPI == 4) ? 0.0f : bias[col];
#pragma unroll
      for (int r = 0; r < 4; ++r) {
        const float v = acc[m][n][r] + bv;
        const long off = (long)(row + r) * N + col;
        if (EPI == 0) {
          Cf[off] = v;
        } else if (EPI == 1) {
          Cb[off] = (bf16)gelu_f(v);
        } else if (EPI == 2) {
          Cf[off] = v;
          Cb[off] = (bf16)v;
        } else if (EPI == 3) {
          Cb[off] = (bf16)v;
        } else {
          Cf[pbase + off] = v;
        }
      }
    }
  }
}

// ---------------- split-K reduce + bias + residual + LayerNorm (short layers) ----------------
__global__ __launch_bounds__(256) void k_redk_ln(const float* __restrict__ P, const float* __restrict__ bias,
                                                 const float* __restrict__ g, const float* __restrict__ bb,
                                                 const float* __restrict__ xin,
                                                 float* __restrict__ xo, bf16* __restrict__ xbo,
                                                 int KS, long MN, int Mreal) {
  const int row = blockIdx.x, tid = threadIdx.x;
  const long base = (long)row * ED;
  __shared__ float red[4];
  if (row >= Mreal) {
#pragma unroll
    for (int e = 0; e < 3; ++e) { xo[base + tid + e * 256] = 0.0f; xbo[base + tid + e * 256] = (bf16)0.0f; }
    return;
  }
  float v[3];
#pragma unroll
  for (int e = 0; e < 3; ++e) {
    const int c = tid + e * 256;
    float a = bias[c] + xin[base + c];
    for (int ks = 0; ks < KS; ++ks) a += P[(long)ks * MN + base + c];
    v[e] = a;
  }
  const float mean = block_sum(v[0] + v[1] + v[2], red, tid) * (1.0f / ED);
  float sq = 0.0f;
#pragma unroll
  for (int e = 0; e < 3; ++e) { const float dd = v[e] - mean; sq += dd * dd; }
  const float var = block_sum(sq, red, tid) * (1.0f / ED);
  const float rs = rsqrtf(var + 1e-5f);
#pragma unroll
  for (int e = 0; e < 3; ++e) {
    const int c = tid + e * 256;
    const float o = (v[e] - mean) * rs * g[c] + bb[c];
    xo[base + c] = o;
    xbo[base + c] = (bf16)o;
  }
}

// ---------------- V repack (pre layers): heads V -> global vT[bh][64][VTS] ----------------
__global__ __launch_bounds__(256) void k_vrepack(const bf16* __restrict__ heads, bf16* __restrict__ vT) {
  const int bh = blockIdx.x;
  const int b = bh / NH, n = bh % NH;
  const int tid = threadIdx.x;
  __shared__ __align__(16) bf16 vTl[64 * 232];
  for (int task = tid; task < 224 * 8; task += 256) {
    const int j = task >> 3, c8 = (task & 7) * 8;
    bf16x8 vv = {};
    if (j < TT1) vv = *(const bf16x8*)&heads[((long)(j * NB + b)) * (3 * ED) + 2 * ED + n * 64 + c8];
#pragma unroll
    for (int e = 0; e < 8; ++e) {
      const int d = c8 + e;
      vTl[d * 232 + (j ^ (((d >> 3) & 3) << 3))] = vv[e];
    }
  }
  __syncthreads();
  bf16* dst = vT + (long)bh * 64 * VTS;
  for (int task = tid; task < 64 * 28; task += 256) {
    const int d = task / 28, u = task % 28;
    const int j0 = u * 8;
    const int x = ((d >> 3) & 3) << 3;
    *(bf16x8*)&dst[d * VTS + j0] = *(const bf16x8*)&vTl[d * 232 + (j0 ^ x)];
  }
}

// ---------------- fused PRE-stack attention: 1-D grid 2688 = 8 XCD groups x 336 ----------------
// Sl stride 201 (odd, bank-spread); probl overlays Sl (barrier-separated aliasing).
// LDS ~26.9 KB -> 6 blocks/CU. Div-free rel-shift scatter (s = a+b+1).
__global__ __launch_bounds__(256) void k_attn_pre(
    const bf16* __restrict__ heads, const float* __restrict__ rwb, const float* __restrict__ rrb,
    const bf16* __restrict__ rkb_l, const bf16* __restrict__ vT, bf16* __restrict__ avb) {
  const int dsp = blockIdx.x;
  const int logical = (dsp & 7) * 336 + (dsp >> 3);
  const int bh = logical / 7;
  const int r0 = (logical - bh * 7) * 32;
  const int b = bh / NH, n = bh % NH;
  const int tid = threadIdx.x;
  const int l = tid & 63, w = tid >> 6;
  const int fr = l & 15;
  const int fc = 8 * (l >> 4);
  __shared__ __align__(16) char smem[32 * SLP * 4];   // Sl (fp32) overlaid with probl (bf16)
  float* Sl = (float*)smem;
  bf16* probl = (bf16*)smem;                          // [32][232] bf16 = 14.8 KB < 25.1 KB
  __shared__ float red8[256];
  __shared__ float rstat[32];

  // ---- phase 1: AC ----
  {
    const int ti = w & 1;
    const int ar = r0 + ti * 16 + fr;
    bf16x8 qa0 = {}, qa1 = {};
    if (ar < TT1) {
      const bf16* qp = &heads[((long)(ar * NB + b)) * (3 * ED) + n * 64];
      qa0 = *(const bf16x8*)(qp + fc);
      qa1 = *(const bf16x8*)(qp + 32 + fc);
    }
    bf16x8 q0, q1;
#pragma unroll
    for (int e = 0; e < 8; ++e) {
      q0[e] = (bf16)((float)qa0[e] + rwb[n * 64 + fc + e]);
      q1[e] = (bf16)((float)qa1[e] + rwb[n * 64 + 32 + fc + e]);
    }
    auto ldk = [&](int tj, bf16x8& k0, bf16x8& k1) {
      const int br = tj * 16 + fr;
      k0 = bf16x8{}; k1 = bf16x8{};
      if (br < TT1) {
        const bf16* kp = &heads[((long)(br * NB + b)) * (3 * ED) + ED + n * 64];
        k0 = *(const bf16x8*)(kp + fc);
        k1 = *(const bf16x8*)(kp + 32 + fc);
      }
    };
    bf16x8 k0, k1, nk0, nk1;
    const int tj0 = w >> 1;
    ldk(tj0, k0, k1);
    for (int tj = tj0; tj < 13; tj += 2) {
      if (tj + 2 < 13) ldk(tj + 2, nk0, nk1);
      f32x4 c = {};
      c = __builtin_amdgcn_mfma_f32_16x16x32_bf16(q0, k0, c, 0, 0, 0);
      c = __builtin_amdgcn_mfma_f32_16x16x32_bf16(q1, k1, c, 0, 0, 0);
      const int scol = tj * 16 + fr;
      const int srb = ti * 16 + 4 * (l >> 4);
#pragma unroll
      for (int r = 0; r < 4; ++r) Sl[(srb + r) * SLP + scol] = SCL * c[r];
      k0 = nk0; k1 = nk1;
    }
  }
  __syncthreads();

  // ---- phase 2: BD with div-free scatter ----
  {
    bf16x8 qr0[3], qr1[3];
#pragma unroll
    for (int ta = 0; ta < 3; ++ta) {
      const int ar = r0 + ta * 16 + fr;
      bf16x8 qa0 = {}, qa1 = {};
      if (ar < TT1) {
        const bf16* qp = &heads[((long)(ar * NB + b)) * (3 * ED) + n * 64];
        qa0 = *(const bf16x8*)(qp + fc);
        qa1 = *(const bf16x8*)(qp + 32 + fc);
      }
#pragma unroll
      for (int e = 0; e < 8; ++e) {
        qr0[ta][e] = (bf16)((float)qa0[e] + rrb[n * 64 + fc + e]);
        qr1[ta][e] = (bf16)((float)qa1[e] + rrb[n * 64 + 32 + fc + e]);
      }
    }
    auto ldr = [&](int tb, bf16x8& g0, bf16x8& g1) {
      const int br = tb * 16 + fr;
      const bf16* rp = &rkb_l[((long)n * TPM + br) * 64];
      g0 = *(const bf16x8*)(rp + fc);
      g1 = *(const bf16x8*)(rp + 32 + fc);
    };
    bf16x8 g0, g1, ng0, ng1;
    if (w < 13) ldr(w, g0, g1);
    for (int tb = w; tb < 13; tb += 4) {
      if (tb + 4 < 13) ldr(tb + 4, ng0, ng1);
#pragma unroll
      for (int ta = 0; ta < 3; ++ta) {
        f32x4 c = {};
        c = __builtin_amdgcn_mfma_f32_16x16x32_bf16(qr0[ta], g0, c, 0, 0, 0);
        c = __builtin_amdgcn_mfma_f32_16x16x32_bf16(qr1[ta], g1, c, 0, 0, 0);
        const int bcol = tb * 16 + fr;
        const int ab = r0 + ta * 16 + 4 * (l >> 4);
#pragma unroll
        for (int r = 0; r < 4; ++r) {
          const int a = ab + r;
          if (a < TT1 && bcol < TT1) {
            const int s = a + bcol + 1;
            const int i = (s < TT1) ? (a - 1) : a;
            const int j = (s < TT1) ? s : (s - TT1);
            const int li = i - r0;
            if (li >= 0 && li < 32) Sl[li * SLP + j] += SCL * c[r];
          }
        }
      }
      g0 = ng0; g1 = ng1;
    }
  }
  __syncthreads();

  // ---- phase 3: row softmax (8 threads per row); P staged in regs, then alias write ----
  const int sr = tid & 31, sg = tid >> 5;
  const bool rowok = (r0 + sr) < TT1;
  const int j0 = sg * 25;
  const int j1 = (j0 + 25 < TT1) ? j0 + 25 : TT1;
  float pm = -3.0e38f;
  if (rowok) {
    for (int j = j0; j < j1; ++j) pm = fmaxf(pm, Sl[sr * SLP + j]);
  }
  red8[sr * 8 + sg] = pm;
  __syncthreads();
  if (tid < 32) {
    float m0 = red8[tid * 8];
#pragma unroll
    for (int q = 1; q < 8; ++q) m0 = fmaxf(m0, red8[tid * 8 + q]);
    rstat[tid] = m0;
  }
  __syncthreads();
  const float rm = rstat[sr];
  float ps = 0.0f;
  if (rowok) {
    for (int j = j0; j < j1; ++j) {
      const float e = __expf(Sl[sr * SLP + j] - rm);
      Sl[sr * SLP + j] = e;
      ps += e;
    }
  }
  red8[sr * 8 + sg] = ps;
  __syncthreads();
  if (tid < 32) {
    float s0 = 0.0f;
#pragma unroll
    for (int q = 0; q < 8; ++q) s0 += red8[tid * 8 + q];
    rstat[tid] = (s0 > 0.0f) ? 1.0f / s0 : 0.0f;
  }
  __syncthreads();
  {
    const float inv = rstat[sr];
    const int sx = ((sr >> 3) & 3) << 3;
    bf16 hreg[28];
#pragma unroll
    for (int u = 0; u < 28; ++u) {
      const int j = sg * 28 + u;
      const float v = (rowok && j < TT1) ? Sl[sr * SLP + j] * inv : 0.0f;
      hreg[u] = (bf16)v;
    }
    __syncthreads();   // all Sl reads complete before alias writes
#pragma unroll
    for (int u = 0; u < 28; ++u) {
      const int j = sg * 28 + u;
      probl[sr * 232 + (j ^ sx)] = hreg[u];
    }
  }
  __syncthreads();

  // ---- phase 4: PV (P from aliased LDS, V from global vT) ----
  const bf16* vTg = vT + (long)bh * 64 * VTS;
  for (int tt = w; tt < 8; tt += 4) {
    const int ti = tt & 1, dj = tt >> 1;
    const int prow = ti * 16 + fr;
    const int vrow = dj * 16 + fr;
    const int px = ((prow >> 3) & 3) << 3;
    f32x4 c = {};
#pragma unroll
    for (int kk = 0; kk < 224; kk += 32) {
      const int j0v = kk + fc;
      const bf16x8 pa = *(const bf16x8*)&probl[prow * 232 + (j0v ^ px)];
      const bf16x8 vb = *(const bf16x8*)&vTg[vrow * VTS + j0v];
      c = __builtin_amdgcn_mfma_f32_16x16x32_bf16(pa, vb, c, 0, 0, 0);
    }
    const int d = dj * 16 + fr;
    const int ib = ti * 16 + 4 * (l >> 4);
#pragma unroll
    for (int r = 0; r < 4; ++r) {
      const int gi = r0 + ib + r;
      if (gi < TT1) avb[((long)(gi * NB + b)) * ED + n * 64 + d] = (bf16)c[r];
    }
  }
}

// ---------------- fused short-stack attention: one block per (b,h), T=41 ----------------
__global__ __launch_bounds__(256) void k_attn_short(
    const bf16* __restrict__ heads, const float* __restrict__ rwb, const float* __restrict__ rrb,
    const bf16* __restrict__ rkb_l, bf16* __restrict__ avb) {
  const int bh = blockIdx.x;
  const int b = bh / NH, n = bh % NH;
  const int tid = threadIdx.x;
  const int l = tid & 63, w = tid >> 6;
  const int fr = l & 15, fc = 8 * (l >> 4);
  __shared__ float Sl[48 * 49];
  __shared__ __align__(16) bf16 probl[48 * 72];
  __shared__ __align__(16) bf16 vTl[64 * 72];

  for (int task = tid; task < 64 * 8; task += 256) {
    const int j = task >> 3, c8 = (task & 7) * 8;
    bf16x8 vv = {};
    if (j < TT2) vv = *(const bf16x8*)&heads[((long)(j * NB + b)) * (3 * ED) + 2 * ED + n * 64 + c8];
#pragma unroll
    for (int e = 0; e < 8; ++e) {
      const int d = c8 + e;
      vTl[d * 72 + (j ^ (((d >> 3) & 3) << 3))] = vv[e];
    }
  }

  for (int tt = w; tt < 9; tt += 4) {
    const int ti = tt / 3, tj = tt % 3;
    const int ar = ti * 16 + fr;
    const int br = tj * 16 + fr;
    f32x4 c = {};
#pragma unroll
    for (int kk = 0; kk < 64; kk += 32) {
      const int col = kk + fc;
      bf16x8 qa = {}, kb = {};
      if (ar < 44) qa = *(const bf16x8*)&heads[((long)(ar * NB + b)) * (3 * ED) + n * 64 + col];
      if (br < 44) kb = *(const bf16x8*)&heads[((long)(br * NB + b)) * (3 * ED) + ED + n * 64 + col];
      bf16x8 qq;
#pragma unroll
      for (int e = 0; e < 8; ++e) qq[e] = (bf16)((float)qa[e] + rwb[n * 64 + col + e]);
      c = __builtin_amdgcn_mfma_f32_16x16x32_bf16(qq, kb, c, 0, 0, 0);
    }
    const int scol = tj * 16 + fr;
    const int srb = ti * 16 + 4 * (l >> 4);
#pragma unroll
    for (int r = 0; r < 4; ++r) Sl[(srb + r) * 49 + scol] = SCL * c[r];
  }
  __syncthreads();

  for (int tt = w; tt < 9; tt += 4) {
    const int ti = tt / 3, tj = tt % 3;
    const int ar = ti * 16 + fr;
    const int br = tj * 16 + fr;
    f32x4 c = {};
#pragma unroll
    for (int kk = 0; kk < 64; kk += 32) {
      const int col = kk + fc;
      bf16x8 qa = {};
      if (ar < 44) qa = *(const bf16x8*)&heads[((long)(ar * NB + b)) * (3 * ED) + n * 64 + col];
      const bf16x8 rk = *(const bf16x8*)&rkb_l[((long)n * TPM + br) * 64 + col];
      bf16x8 qq;
#pragma unroll
      for (int e = 0; e < 8; ++e) qq[e] = (bf16)((float)qa[e] + rrb[n * 64 + col + e]);
      c = __builtin_amdgcn_mfma_f32_16x16x32_bf16(qq, rk, c, 0, 0, 0);
    }
    const int bcol = tj * 16 + fr;
    const int ab = ti * 16 + 4 * (l >> 4);
#pragma unroll
    for (int r = 0; r < 4; ++r) {
      const int a = ab + r;
      if (a < TT2 && bcol < TT2) {
        const int s = a + bcol + 1;
        const int i = (s < TT2) ? (a - 1) : a;
        const int j = (s < TT2) ? s : (s - TT2);
        if (i >= 0) Sl[i * 49 + j] += SCL * c[r];
      }
    }
  }
  __syncthreads();

  if (tid < 48) {
    const int i = tid;
    const int ix = ((i >> 3) & 3) << 3;
    if (i < TT2) {
      float mx = -3.0e38f;
      for (int j = 0; j < TT2; ++j) mx = fmaxf(mx, Sl[i * 49 + j]);
      float sm = 0.0f;
      for (int j = 0; j < TT2; ++j) { const float e = expf(Sl[i * 49 + j] - mx); Sl[i * 49 + j] = e; sm += e; }
      const float inv = 1.0f / sm;
      for (int j = 0; j < TT2; ++j) probl[i * 72 + (j ^ ix)] = (bf16)(Sl[i * 49 + j] * inv);
      for (int j = TT2; j < 64; ++j) probl[i * 72 + (j ^ ix)] = (bf16)0.0f;
    } else {
      for (int j = 0; j < 64; ++j) probl[i * 72 + (j ^ ix)] = (bf16)0.0f;
    }
  }
  __syncthreads();

  for (int tt = w; tt < 12; tt += 4) {
    const int ti = tt % 3, dj = tt / 3;
    const int prow = ti * 16 + fr;
    const int vrow = dj * 16 + fr;
    const int px = ((prow >> 3) & 3) << 3;
    const int vx = ((vrow >> 3) & 3) << 3;
    f32x4 c = {};
#pragma unroll
    for (int kk = 0; kk < 64; kk += 32) {
      const int j0 = kk + fc;
      const bf16x8 pa = *(const bf16x8*)&probl[prow * 72 + (j0 ^ px)];
      const bf16x8 vb = *(const bf16x8*)&vTl[vrow * 72 + (j0 ^ vx)];
      c = __builtin_amdgcn_mfma_f32_16x16x32_bf16(pa, vb, c, 0, 0, 0);
    }
    const int d = dj * 16 + fr;
    const int ib = ti * 16 + 4 * (l >> 4);
#pragma unroll
    for (int r = 0; r < 4; ++r) {
      const int i = ib + r;
      if (i < TT2) avb[((long)(i * NB + b)) * ED + n * 64 + d] = (bf16)c[r];
    }
  }
}

// ---------------- rk repack: rkall fp32 [rows][nl*768] -> rkb bf16 [l][n][TPM][64] ----------------
__global__ void k_rkrepack(const float* __restrict__ rkall, bf16* __restrict__ rkb,
                           int T, int Ncols, int l0) {
  const int i = blockIdx.x, z = blockIdx.y, d = threadIdx.x;  // block = 768
  const float v = (i < T) ? rkall[(long)i * Ncols + z * ED + d] : 0.0f;
  const int n = d >> 6, dh = d & 63;
  rkb[(((long)(l0 + z) * NH + n) * TPM + i) * 64 + dh] = (bf16)v;
}

// ---------------- residual + LayerNorm (fp32 master, bf16 copy) ----------------
__global__ __launch_bounds__(256) void k_ln(const float* __restrict__ xin, const float* __restrict__ add,
                                            const float* __restrict__ g, const float* __restrict__ bb,
                                            float* __restrict__ xo, bf16* __restrict__ xbo, int Mreal) {
  const int row = blockIdx.x, tid = threadIdx.x;
  const long base = (long)row * ED;
  __shared__ float red[4];
  if (row >= Mreal) {
#pragma unroll
    for (int e = 0; e < 3; ++e) { xo[base + tid + e * 256] = 0.0f; xbo[base + tid + e * 256] = (bf16)0.0f; }
    return;
  }
  float v[3];
#pragma unroll
  for (int e = 0; e < 3; ++e) v[e] = xin[base + tid + e * 256] + add[base + tid + e * 256];
  const float mean = block_sum(v[0] + v[1] + v[2], red, tid) * (1.0f / ED);
  float sq = 0.0f;
#pragma unroll
  for (int e = 0; e < 3; ++e) { const float dd = v[e] - mean; sq += dd * dd; }
  const float var = block_sum(sq, red, tid) * (1.0f / ED);
  const float rs = rsqrtf(var + 1e-5f);
#pragma unroll
  for (int e = 0; e < 3; ++e) {
    const int c = tid + e * 256;
    const float o = (v[e] - mean) * rs * g[c] + bb[c];
    xo[base + c] = o;
    xbo[base + c] = (bf16)o;
  }
}

// ---------------- downsample: segment-mean pool + null token + LN ----------------
__global__ __launch_bounds__(256) void k_down(const float* __restrict__ x, const float* __restrict__ nullt,
                                              const float* __restrict__ g, const float* __restrict__ bb,
                                              float* __restrict__ xo, bf16* __restrict__ xbo) {
  const int row = blockIdx.x, tid = threadIdx.x;
  const long base = (long)row * ED;
  __shared__ float red[4];
  if (row >= TT2 * NB) {
#pragma unroll
    for (int e = 0; e < 3; ++e) { xo[base + tid + e * 256] = 0.0f; xbo[base + tid + e * 256] = (bf16)0.0f; }
    return;
  }
  const int s = row >> 5, b = row & 31;
  float v[3];
  if (s == 0) {
#pragma unroll
    for (int e = 0; e < 3; ++e) v[e] = nullt[tid + e * 256];
  } else {
    const int seg = s - 1;
    const int t0 = (seg == 0) ? 0 : (5 * seg - 4);
    const int cnt = (seg == 0) ? 1 : 5;
#pragma unroll
    for (int e = 0; e < 3; ++e) {
      float a = 0.0f;
      for (int tt = 0; tt < cnt; ++tt) a += x[((long)((t0 + tt) * NB + b)) * ED + tid + e * 256];
      v[e] = a / (float)cnt;
    }
  }
  const float mean = block_sum(v[0] + v[1] + v[2], red, tid) * (1.0f / ED);
  float sq = 0.0f;
#pragma unroll
  for (int e = 0; e < 3; ++e) { const float dd = v[e] - mean; sq += dd * dd; }
  const float var = block_sum(sq, red, tid) * (1.0f / ED);
  const float rs = rsqrtf(var + 1e-5f);
#pragma unroll
  for (int e = 0; e < 3; ++e) {
    const int c = tid + e * 256;
    const float o = (v[e] - mean) * rs * g[c] + bb[c];
    xo[base + c] = o;
    xbo[base + c] = (bf16)o;
  }
}

// ---------------- final token mean (fp32) ----------------
__global__ __launch_bounds__(256) void k_mean(const float* __restrict__ x2, float* __restrict__ xm) {
  const int b = blockIdx.x, tid = threadIdx.x;
#pragma unroll
  for (int e = 0; e < 3; ++e) {
    const int c = tid + e * 256;
    float a = 0.0f;
    for (int s = 0; s < TT2; ++s) a += x2[((long)(s * NB + b)) * ED + c];
    xm[(long)b * ED + c] = a * (1.0f / TT2);
  }
}

// ---------------- classifier head (fp32 dot, wave per (b,n)) ----------------
__global__ __launch_bounds__(256) void k_head(const float* __restrict__ xm, const float* __restrict__ hw,
                                              const float* __restrict__ hbias, float* __restrict__ out) {
  const int gid = blockIdx.x * 4 + (threadIdx.x >> 6);
  const int l = threadIdx.x & 63;
  if (gid >= NB * 1000) return;
  const int b = gid / 1000, n = gid % 1000;
  const float* xr = xm + (long)b * ED;
  const float* wr = hw + (long)n * ED;
  float a = 0.0f;
#pragma unroll
  for (int e = 0; e < 12; ++e) a += xr[l + 64 * e] * wr[l + 64 * e];
#pragma unroll
  for (int o = 32; o; o >>= 1) a += __shfl_xor(a, o);
  if (l == 0) out[(long)b * 1000 + n] = a + hbias[n];
}

// =======================================================================
extern "C" void kernel_launch(void* const* d_in, const int* in_sizes, int n_in,
                              void* d_out, int out_size, void* d_ws, size_t ws_size,
                              hipStream_t stream) {
  const float* in_x     = (const float*)d_in[0];
  const float* patch_w  = (const float*)d_in[1];
  const float* patch_b  = (const float*)d_in[2];
  const float* r_w_bias = (const float*)d_in[3];
  const float* r_r_bias = (const float*)d_in[4];
  const float* qkv_w    = (const float*)d_in[5];
  const float* qkv_b    = (const float*)d_in[6];
  const float* rnet_w   = (const float*)d_in[7];
  const float* rnet_b   = (const float*)d_in[8];
  const float* onet_w   = (const float*)d_in[9];
  const float* onet_b   = (const float*)d_in[10];
  const float* ln1_g    = (const float*)d_in[11];
  const float* ln1_b    = (const float*)d_in[12];
  const float* ff1_w    = (const float*)d_in[13];
  const float* ff1_b    = (const float*)d_in[14];
  const float* ff2_w    = (const float*)d_in[15];
  const float* ff2_b    = (const float*)d_in[16];
  const float* ln2_g    = (const float*)d_in[17];
  const float* ln2_b    = (const float*)d_in[18];
  const float* null_tok = (const float*)d_in[19];
  const float* down_g   = (const float*)d_in[20];
  const float* down_b   = (const float*)d_in[21];
  const float* head_w   = (const float*)d_in[22];
  const float* head_b   = (const float*)d_in[23];
  float* out = (float*)d_out;

  char* base = (char*)d_ws;
  size_t off = 0;
  auto take = [&](size_t bytes) -> char* {
    char* r = base + off;
    off += (bytes + 255) & ~(size_t)255;
    return r;
  };

  // persistent
  float* x    = (float*)take((size_t)MM1 * ED * 4);
  bf16*  xb   = (bf16*)take((size_t)MM1 * ED * 2);
  float* x2   = (float*)take((size_t)MM2 * ED * 4);
  bf16*  xb2  = (bf16*)take((size_t)MM2 * ED * 2);
  bf16*  rkb  = (bf16*)take((size_t)LTOT * NH * TPM * 64 * 2);
  bf16*  rbf  = (bf16*)take((size_t)256 * ED * 2);
  bf16*  r2bf = (bf16*)take((size_t)128 * ED * 2);
  float* xm   = (float*)take((size_t)NB * ED * 4);

  // Arena W: pre-layer weights; setup overlay = wrnet + wpatch
  char* arenaW = take((size_t)(2304 * 768 + 768 * 768 + 3072 * 768 + 768 * 3072) * 2);
  bf16* wq = (bf16*)arenaW;
  bf16* wo = wq + (size_t)2304 * 768;
  bf16* w1 = wo + (size_t)768 * 768;
  bf16* w2 = w1 + (size_t)3072 * 768;
  bf16* wrnet  = (bf16*)arenaW;
  bf16* wpatch = wrnet + (size_t)LTOT * 768 * 768;

  // Arena Q: overlays: A0 (setup im2col), vT (pre-attn), P (short split-K)
  char* arenaQ = take((size_t)MM1 * ED * 2 + (size_t)4 * MM2 * ED * 4);
  bf16*  A0 = (bf16*)arenaQ;
  bf16*  vT = (bf16*)arenaQ;
  float* P  = (float*)arenaQ;

  // Arena H: heads(bf16); setup overlay = rkall1+rkall2
  char* arenaH = take((size_t)MM1 * 3 * ED * 2);
  bf16*  headsb = (bf16*)arenaH;
  float* rkall1 = (float*)arenaH;
  float* rkall2 = (float*)(arenaH + (size_t)256 * 1536 * 4);

  // Arena S: {avb, gout, hb}
  char* arenaS = take((size_t)MM1 * ED * 2 + (size_t)MM1 * ED * 4 + (size_t)MM1 * FFD * 2);
  bf16*  avb  = (bf16*)arenaS;
  float* gout = (float*)(arenaS + (size_t)MM1 * ED * 2);
  bf16*  hb   = (bf16*)(arenaS + (size_t)MM1 * ED * 2 + (size_t)MM1 * ED * 4);

  if (off > ws_size) return;

  // ---- setup ----
  k_posemb<<<dim3(256), dim3(768), 0, stream>>>(rbf, TT1);
  k_posemb<<<dim3(128), dim3(768), 0, stream>>>(r2bf, TT2);
  k_cvt<<<dim3(2048), dim3(256), 0, stream>>>(rnet_w, wrnet, (long)LTOT * 768 * 768 / 8);
  k_cvt<<<dim3(288), dim3(256), 0, stream>>>(patch_w, wpatch, (long)768 * 768 / 8);
  k_im2col<<<dim3((MM1 * ED + 255) / 256), dim3(256), 0, stream>>>(in_x, A0);
  k_gemm<2><<<dim3(6, 49, 1), dim3(256), 0, stream>>>(A0, wpatch, patch_b, x, xb, MM1, ED, ED, ED);
  k_gemm<0><<<dim3(12, 2, 1), dim3(256), 0, stream>>>(rbf, wrnet, rnet_b, rkall1, nullptr, 256, 1536, ED, ED);
  k_gemm<0><<<dim3(48, 1, 1), dim3(256), 0, stream>>>(r2bf, wrnet + (size_t)2 * 768 * 768, rnet_b + 2 * 768,
                                                      rkall2, nullptr, 128, 6144, ED, ED);
  k_rkrepack<<<dim3(TPM, 2), dim3(768), 0, stream>>>(rkall1, rkb, TT1, 1536, 0);
  k_rkrepack<<<dim3(48, 8), dim3(768), 0, stream>>>(rkall2, rkb, TT2, 6144, 2);

  // ---- transformer layers ----
  for (int l = 0; l < LTOT; ++l) {
    const bool pre = (l < 2);
    const int Mp = pre ? MM1 : MM2;
    const int Mreal = pre ? MM1 : M2R;
    float* xcur = pre ? x : x2;
    bf16* xbcur = pre ? xb : xb2;

    k_cvt4<<<dim3(2048), dim3(256), 0, stream>>>(
        qkv_w + (size_t)l * 2304 * 768, onet_w + (size_t)l * 768 * 768,
        ff1_w + (size_t)l * 3072 * 768, ff2_w + (size_t)l * 768 * 3072,
        wq, wo, w1, w2, 2304 * 768 / 8, 768 * 768 / 8, 3072 * 768 / 8, 768 * 3072 / 8);

    k_gemm<3><<<dim3(18, Mp / 128, 1), dim3(256), 0, stream>>>(xbcur, wq, qkv_b + (size_t)l * 2304,
                                                               nullptr, headsb, Mp, 3 * ED, ED, ED);
    if (pre) {
      k_vrepack<<<dim3(BHN), dim3(256), 0, stream>>>(headsb, vT);
      k_attn_pre<<<dim3(7 * BHN), dim3(256), 0, stream>>>(
          headsb, r_w_bias, r_r_bias, rkb + (size_t)l * NH * TPM * 64, vT, avb);
      k_gemm<0><<<dim3(6, Mp / 128, 1), dim3(256), 0, stream>>>(avb, wo, onet_b + (size_t)l * 768,
                                                                gout, nullptr, Mp, ED, ED, ED);
      k_ln<<<dim3(Mp), dim3(256), 0, stream>>>(xcur, gout, ln1_g + (size_t)l * 768, ln1_b + (size_t)l * 768,
                                               xcur, xbcur, Mreal);
      k_gemm<1><<<dim3(24, Mp / 128, 1), dim3(256), 0, stream>>>(xbcur, w1, ff1_b + (size_t)l * 3072,
                                                                 nullptr, hb, Mp, FFD, ED, ED);
      k_gemm<0><<<dim3(6, Mp / 128, 1), dim3(256), 0, stream>>>(hb, w2, ff2_b + (size_t)l * 768,
                                                                gout, nullptr, Mp, ED, FFD, FFD);
      k_ln<<<dim3(Mp), dim3(256), 0, stream>>>(xcur, gout, ln2_g + (size_t)l * 768, ln2_b + (size_t)l * 768,
                                               xcur, xbcur, Mreal);
    } else {
      k_attn_short<<<dim3(BHN), dim3(256), 0, stream>>>(
          headsb, r_w_bias, r_r_bias, rkb + (size_t)l * NH * TPM * 64, avb);
      // wo: split-K x2 -> partials -> fused reduce+residual+LN1
      k_gemm<4><<<dim3(6, Mp / 128, 2), dim3(256), 0, stream>>>(avb, wo, nullptr,
                                                                P, nullptr, Mp, ED, 384, ED);
      k_redk_ln<<<dim3(Mp), dim3(256), 0, stream>>>(P, onet_b + (size_t)l * 768,
                                                    ln1_g + (size_t)l * 768, ln1_b + (size_t)l * 768,
                                                    xcur, xcur, xbcur, 2, (long)Mp * ED, Mreal);
      k_gemm<1><<<dim3(24, Mp / 128, 1), dim3(256), 0, stream>>>(xbcur, w1, ff1_b + (size_t)l * 3072,
                                                                 nullptr, hb, Mp, FFD, ED, ED);
      // ff2: split-K x4 -> partials -> fused reduce+residual+LN2
      k_gemm<4><<<dim3(6, Mp / 128, 4), dim3(256), 0, stream>>>(hb, w2, nullptr,
                                                                P, nullptr, Mp, ED, 768, FFD);
      k_redk_ln<<<dim3(Mp), dim3(256), 0, stream>>>(P, ff2_b + (size_t)l * 768,
                                                    ln2_g + (size_t)l * 768, ln2_b + (size_t)l * 768,
                                                    xcur, xcur, xbcur, 4, (long)Mp * ED, Mreal);
    }

    if (l == 1) {
      k_down<<<dim3(MM2), dim3(256), 0, stream>>>(x, null_tok, down_g, down_b, x2, xb2);
    }
  }

  // ---- final: token mean + classifier head (fp32) ----
  k_mean<<<dim3(NB), dim3(256), 0, stream>>>(x2, xm);
  k_head<<<dim3(8000), dim3(256), 0, stream>>>(xm, head_w, head_b, out);
}